// Round 1
// baseline (2278.128 us; speedup 1.0000x reference)
//
#include <hip/hip_runtime.h>
#include <cmath>

#define B_   128
#define N_   39
#define KNN_ 10
#define H_   256
#define K1_  32
#define K2_  26
#define K3_  21

static inline int cdiv(int a, int b) { return (a + b - 1) / b; }

// wc[k][c] = c<H ? w_top[k][c]-w_bot[k][c] : w_bot[k][c-H]   (w is (2F,H) row-major)
__global__ void wcat_kernel(const float* __restrict__ w, int F, int Hc, float* __restrict__ wc) {
  int t = blockIdx.x * blockDim.x + threadIdx.x;
  int total = F * 2 * Hc;
  if (t >= total) return;
  int k = t / (2 * Hc);
  int c = t - k * 2 * Hc;
  if (c < Hc) wc[t] = w[k * Hc + c] - w[(F + k) * Hc + c];
  else        wc[t] = w[(F + k) * Hc + (c - Hc)];
}

__global__ void degree_kernel(const float* __restrict__ adj, float* __restrict__ deg) {
  int t = blockIdx.x * blockDim.x + threadIdx.x;
  if (t >= B_ * N_) return;
  const float* row = adj + (size_t)t * N_;
  float s = 0.f;
  for (int j = 0; j < N_; ++j) s += row[j];
  deg[t] = s;
}

// G[b,i,j] = dot(x[b,i], x[b,j])
__global__ void gram_kernel(const float* __restrict__ x, int n, int F, float* __restrict__ G) {
  int t = blockIdx.x * blockDim.x + threadIdx.x;
  if (t >= B_ * n * n) return;
  int b = t / (n * n);
  int r = t - b * n * n;
  int i = r / n;
  int j = r - i * n;
  const float* xi = x + (size_t)(b * n + i) * F;
  const float* xj = x + (size_t)(b * n + j) * F;
  float acc = 0.f;
  if ((F & 3) == 0) {
    const float4* a4 = (const float4*)xi;
    const float4* b4 = (const float4*)xj;
    int F4 = F >> 2;
    for (int f = 0; f < F4; ++f) {
      float4 a = a4[f], bb = b4[f];
      acc += a.x * bb.x + a.y * bb.y + a.z * bb.z + a.w * bb.w;
    }
  } else {
    for (int f = 0; f < F; ++f) acc += xi[f] * xj[f];
  }
  G[t] = acc;
}

// K nearest (smallest d = Gii+Gjj-2Gij), ties -> lowest index (stable like lax.top_k)
__global__ void knn_kernel(const float* __restrict__ G, int n, int* __restrict__ idx) {
  int t = blockIdx.x * blockDim.x + threadIdx.x;
  if (t >= B_ * n) return;
  int b = t / n;
  int i = t - b * n;
  const float* Gb = G + (size_t)b * n * n;
  float d[N_];
  float gii = Gb[i * n + i];
  for (int j = 0; j < n; ++j) d[j] = gii + Gb[j * n + j] - 2.f * Gb[i * n + j];
  int* out = idx + (size_t)t * KNN_;
  for (int kk = 0; kk < KNN_; ++kk) {
    int bj = 0; float bv = d[0];
    for (int j = 1; j < n; ++j) { if (d[j] < bv) { bv = d[j]; bj = j; } }
    out[kk] = bj;
    d[bj] = INFINITY;
  }
}

// C = A(MxK) @ W(KxN) [+bias] [relu]; row-major; generic bounds
#define BM 64
#define BN 64
#define BK 16
__global__ __launch_bounds__(256) void gemm_kernel(
    const float* __restrict__ A, const float* __restrict__ W, const float* __restrict__ bias,
    float* __restrict__ C, int M, int N, int K, int act) {
  __shared__ float As[BK][BM + 4];
  __shared__ float Bs[BK][BN + 4];
  int tid = threadIdx.x;
  int tx = tid & 15, ty = tid >> 4;
  int row0 = blockIdx.y * BM, col0 = blockIdx.x * BN;
  float c[4][4] = {};
  for (int k0 = 0; k0 < K; k0 += BK) {
    for (int e = tid; e < BM * BK; e += 256) {
      int m = e / BK, kk = e - m * BK;
      int row = row0 + m, k = k0 + kk;
      As[kk][m] = (row < M && k < K) ? A[(size_t)row * K + k] : 0.f;
    }
    for (int e = tid; e < BK * BN; e += 256) {
      int kk = e / BN, nn = e - kk * BN;
      int k = k0 + kk, col = col0 + nn;
      Bs[kk][nn] = (k < K && col < N) ? W[(size_t)k * N + col] : 0.f;
    }
    __syncthreads();
#pragma unroll
    for (int kk = 0; kk < BK; ++kk) {
      float a[4], b[4];
#pragma unroll
      for (int i = 0; i < 4; ++i) a[i] = As[kk][ty * 4 + i];
#pragma unroll
      for (int j = 0; j < 4; ++j) b[j] = Bs[kk][tx * 4 + j];
#pragma unroll
      for (int i = 0; i < 4; ++i)
#pragma unroll
        for (int j = 0; j < 4; ++j) c[i][j] += a[i] * b[j];
    }
    __syncthreads();
  }
  for (int i = 0; i < 4; ++i) {
    int row = row0 + ty * 4 + i;
    if (row >= M) continue;
    for (int j = 0; j < 4; ++j) {
      int col = col0 + tx * 4 + j;
      if (col >= N) continue;
      float v = c[i][j] + (bias ? bias[col] : 0.f);
      if (act == 1) v = fmaxf(v, 0.f);
      C[(size_t)row * N + col] = v;
    }
  }
}

// AB row r: [0..Hc) = xi@(Wt-Wb), [Hc..2Hc) = xi@Wb.  out = max_k relu(Ai + b + Bm[nbr]) [tanh]
__global__ void edge_agg_kernel(const float* __restrict__ AB, const float* __restrict__ bias,
                                const int* __restrict__ idx, int n, int Hc, int act,
                                float* __restrict__ out) {
  int t = blockIdx.x * blockDim.x + threadIdx.x;
  if (t >= B_ * n * Hc) return;
  int r = t / Hc, h = t - r * Hc;
  int b = r / n;
  int s2 = 2 * Hc;
  float av = AB[(size_t)r * s2 + h] + bias[h];
  const int* ir = idx + (size_t)r * KNN_;
  int base = b * n;
  float m = -INFINITY;
  for (int k = 0; k < KNN_; ++k) {
    float v = av + AB[(size_t)(base + ir[k]) * s2 + Hc + h];
    v = fmaxf(v, 0.f);
    m = fmaxf(m, v);
  }
  if (act == 2) m = tanhf(m);
  out[t] = m;
}

__global__ void bn_stats_kernel(const float* __restrict__ x, int M, float* __restrict__ mv) {
  int c = blockIdx.x;  // column, H_ blocks
  double s = 0.0, s2 = 0.0;
  for (int r = threadIdx.x; r < M; r += 256) {
    double v = (double)x[(size_t)r * H_ + c];
    s += v; s2 += v * v;
  }
  __shared__ double sh[256], sh2[256];
  sh[threadIdx.x] = s; sh2[threadIdx.x] = s2;
  __syncthreads();
  for (int o = 128; o; o >>= 1) {
    if (threadIdx.x < o) { sh[threadIdx.x] += sh[threadIdx.x + o]; sh2[threadIdx.x] += sh2[threadIdx.x + o]; }
    __syncthreads();
  }
  if (threadIdx.x == 0) {
    double mean = sh[0] / M;
    double var = sh2[0] / M - mean * mean;
    mv[c] = (float)mean;
    mv[H_ + c] = (float)var;
  }
}

__global__ void bn_apply_kernel(const float* __restrict__ x, const float* __restrict__ mv,
                                const float* __restrict__ g, const float* __restrict__ bb,
                                int M, float* __restrict__ out) {
  int t = blockIdx.x * blockDim.x + threadIdx.x;
  if (t >= M * H_) return;
  int h = t & (H_ - 1);
  float mean = mv[h], var = mv[H_ + h];
  float v = (x[t] - mean) * (1.f / sqrtf(var + 1e-5f)) * g[h] + bb[h];
  out[t] = fmaxf(v, 0.f);
}

// one wave per row: y[r] = dot(x[r,:K], w) [+bias] [relu]
__global__ void rowdot_kernel(const float* __restrict__ x, const float* __restrict__ w,
                              int M, int K, const float* __restrict__ bias, int act,
                              float* __restrict__ y) {
  int wid = (blockIdx.x * blockDim.x + threadIdx.x) >> 6;
  int lane = threadIdx.x & 63;
  if (wid >= M) return;
  const float* xr = x + (size_t)wid * K;
  float s = 0.f;
  for (int k = lane; k < K; k += 64) s += xr[k] * w[k];
  for (int off = 32; off; off >>= 1) s += __shfl_down(s, off, 64);
  if (lane == 0) {
    float v = s + (bias ? bias[0] : 0.f);
    if (act == 1) v = fmaxf(v, 0.f);
    y[wid] = v;
  }
}

// s[b,i] = dinv_i * sum_j (adj+I)_ij * dinv_j * y_j + pb ; dinv = rsqrt(rowsum(adj+I))
__global__ void gcn_score_kernel(const float* __restrict__ adj, const float* __restrict__ y,
                                 const float* __restrict__ pb, int n, float* __restrict__ s) {
  int b = blockIdx.x;
  __shared__ float dinv[64], ys[64];
  int i = threadIdx.x;
  if (i < n) {
    const float* ar = adj + ((size_t)b * n + i) * n;
    float sum = 1.f;
    for (int j = 0; j < n; ++j) sum += ar[j];
    dinv[i] = 1.f / sqrtf(sum);
    ys[i] = y[b * n + i];
  }
  __syncthreads();
  if (i < n) {
    const float* ar = adj + ((size_t)b * n + i) * n;
    float acc = 0.f;
    for (int j = 0; j < n; ++j) {
      float a = ar[j] + (i == j ? 1.f : 0.f);
      acc += a * dinv[j] * ys[j];
    }
    s[b * n + i] = dinv[i] * acc + pb[0];
  }
}

// descending top-k per graph, stable ties (lowest index first)
__global__ void topk_kernel(const float* __restrict__ s, int n, int k,
                            float* __restrict__ top, int* __restrict__ loc) {
  int b = blockIdx.x * blockDim.x + threadIdx.x;
  if (b >= B_) return;
  float sc[N_];
  for (int j = 0; j < n; ++j) sc[j] = s[b * n + j];
  for (int t = 0; t < k; ++t) {
    int bj = 0; float bv = sc[0];
    for (int j = 1; j < n; ++j) { if (sc[j] > bv) { bv = sc[j]; bj = j; } }
    top[b * k + t] = bv;
    loc[b * k + t] = bj;
    sc[bj] = -INFINITY;
  }
}

__global__ void pool_gather_kernel(const float* __restrict__ h, const float* __restrict__ top,
                                   const int* __restrict__ loc, int n, int k,
                                   float* __restrict__ xp, int* __restrict__ perm) {
  int t = blockIdx.x * blockDim.x + threadIdx.x;
  if (t >= B_ * k * H_) return;
  int r = t / H_, hh = t - r * H_;
  int b = r / k;
  int l = loc[r];
  xp[t] = h[((size_t)(b * n + l)) * H_ + hh] * tanhf(top[r]);
  if (hh == 0) perm[r] = b * n + l;
}

__global__ void adj_gather_kernel(const float* __restrict__ adj, const int* __restrict__ loc,
                                  int n, int k, float* __restrict__ adjp) {
  int t = blockIdx.x * blockDim.x + threadIdx.x;
  if (t >= B_ * k * k) return;
  int b = t / (k * k);
  int r = t - b * k * k;
  int t1 = r / k, t2 = r - t1 * k;
  adjp[t] = adj[((size_t)b * n + loc[b * k + t1]) * n + loc[b * k + t2]];
}

// dst[i1[i2[r]] or i1[r]] = src[r]   (dst pre-zeroed)
__global__ void scatter_kernel(const float* __restrict__ src, const int* __restrict__ i1,
                               const int* __restrict__ i2, int rows, float* __restrict__ dst) {
  int t = blockIdx.x * blockDim.x + threadIdx.x;
  if (t >= rows * H_) return;
  int r = t / H_, h = t - r * H_;
  int tgt = i2 ? i1[i2[r]] : i1[r];
  dst[(size_t)tgt * H_ + h] = src[t];
}

__global__ void gtpred_kernel(const float* __restrict__ deg, const float* __restrict__ xdeg,
                              const int* __restrict__ perm, int M,
                              float* __restrict__ gt, float* __restrict__ pred) {
  int t = blockIdx.x * blockDim.x + threadIdx.x;
  if (t >= M) return;
  int p = perm[t];
  gt[t] = deg[p];
  pred[t] = xdeg[p];
}

__global__ void readout_kernel(const float* __restrict__ xp, int k, int acc, float* __restrict__ z) {
  int t = blockIdx.x * blockDim.x + threadIdx.x;
  if (t >= B_ * H_) return;
  int b = t / H_, h = t - b * H_;
  float mx = -INFINITY, sm = 0.f;
  for (int tt = 0; tt < k; ++tt) {
    float v = xp[((size_t)b * k + tt) * H_ + h];
    mx = fmaxf(mx, v);
    sm += v;
  }
  float* zb = z + (size_t)b * 2 * H_;
  float mean = sm / (float)k;
  if (acc) { zb[h] += mx; zb[H_ + h] += mean; }
  else     { zb[h] = mx;  zb[H_ + h] = mean; }
}

__global__ void softmax2_kernel(const float* __restrict__ logits, float* __restrict__ probs) {
  int b = blockIdx.x * blockDim.x + threadIdx.x;
  if (b >= B_) return;
  float a = logits[2 * b], c = logits[2 * b + 1];
  float m = fmaxf(a, c);
  float ea = expf(a - m), ec = expf(c - m);
  float inv = 1.f / (ea + ec);
  probs[2 * b] = ea * inv;
  probs[2 * b + 1] = ec * inv;
}

extern "C" void kernel_launch(void* const* d_in, const int* in_sizes, int n_in,
                              void* d_out, int out_size, void* d_ws, size_t ws_size,
                              hipStream_t stream) {
  auto in = [&](int i) { return (const float*)d_in[i]; };
  const float* x      = in(0);
  const float* adj    = in(1);
  const float* w_mlp1 = in(2);  const float* b_mlp1 = in(3);
  const float* w_mlp2 = in(4);  const float* b_mlp2 = in(5);
  const float* w_mlp3 = in(6);  const float* b_mlp3 = in(7);
  const float* w_mlp6 = in(8);  const float* b_mlp6 = in(9);
  const float* bn1_g = in(10);  const float* bn1_b = in(11);
  const float* bn2_g = in(12);  const float* bn2_b = in(13);
  const float* bn3_g = in(14);  const float* bn3_b = in(15);
  const float* p1_w = in(16);   const float* p1_b = in(17);
  const float* p2_w = in(18);   const float* p2_b = in(19);
  const float* p3_w = in(20);   const float* p3_b = in(21);
  const float* lin1_w = in(22); const float* lin1_b = in(23);
  const float* lin2_w = in(24); const float* lin2_b = in(25);
  const float* lin3_w = in(26); const float* lin3_b = in(27);
  const float* lin4_w = in(28); const float* lin4_b = in(29);
  const float* lin5_w = in(30); const float* lin5_b = in(31);
  const float* lin6_w = in(32); const float* lin6_b = in(33);

  float* out = (float*)d_out;
  float* out_probs = out;                      // 128*2
  float* out_dec1  = out_probs + 256;          // 4992*39
  float* out_dec2  = out_dec1 + 4992 * 39;
  float* out_dec3  = out_dec2 + 4992 * 39;
  float* out_gt1   = out_dec3 + 4992 * 39;     // 4096
  float* out_pred1 = out_gt1 + 4096;           // 4096
  float* out_gt2   = out_pred1 + 4096;         // 3328
  float* out_pred2 = out_gt2 + 3328;
  float* out_gt3   = out_pred2 + 3328;         // 2688
  float* out_pred3 = out_gt3 + 2688;

  char* base = (char*)d_ws;
  size_t off = 0;
  auto allocf = [&](size_t n) -> float* {
    float* p = (float*)(base + off);
    off += ((n * sizeof(float) + 255) & ~(size_t)255);
    return p;
  };
  auto alloci = [&](size_t n) -> int* {
    int* p = (int*)(base + off);
    off += ((n * sizeof(int) + 255) & ~(size_t)255);
    return p;
  };

  float* wcat1 = allocf(39 * 512);
  float* wcat2 = allocf(256 * 512);
  float* wcat3 = allocf(256 * 512);
  float* wcat6 = allocf(256 * 78);
  float* deg   = allocf(4992);
  float* xdeg  = allocf(4992);
  float* ybuf  = allocf(4992);
  float* sbuf  = allocf(4992);
  float* stats = allocf(512);
  float* G     = allocf(128 * 39 * 39);
  int*   idxb  = alloci(4992 * KNN_);
  float* AB    = allocf((size_t)4992 * 512);
  float* t1    = allocf((size_t)4992 * 256);
  float* t2    = allocf((size_t)4992 * 256);
  float* hbuf  = allocf((size_t)4992 * 256);
  float* xp    = allocf((size_t)4096 * 256);
  float* xout  = allocf((size_t)4992 * 256);
  float* adj1  = allocf(128 * 32 * 32);
  float* adj2  = allocf(128 * 26 * 26);
  float* top1  = allocf(4096);
  float* top2  = allocf(3328);
  float* top3  = allocf(2688);
  int* loc1 = alloci(4096); int* loc2 = alloci(3328); int* loc3 = alloci(2688);
  int* perm1 = alloci(4096); int* perm2 = alloci(3328); int* perm3 = alloci(2688);
  float* z  = allocf(128 * 512);
  float* z1 = allocf(128 * 256);
  float* z2 = allocf(128 * 128);
  float* logits = allocf(256);
  if (off > ws_size) return;  // workspace too small — fail loudly via poisoned output

  auto edge_conv = [&](const float* xin, int n, int F, const float* wcat, const float* bias,
                       int Hout, int act, float* outbuf) {
    int M = B_ * n;
    gram_kernel<<<cdiv(B_ * n * n, 256), 256, 0, stream>>>(xin, n, F, G);
    knn_kernel<<<cdiv(M, 256), 256, 0, stream>>>(G, n, idxb);
    dim3 gg(cdiv(2 * Hout, BN), cdiv(M, BM));
    gemm_kernel<<<gg, 256, 0, stream>>>(xin, wcat, nullptr, AB, M, 2 * Hout, F, 0);
    edge_agg_kernel<<<cdiv(M * Hout, 256), 256, 0, stream>>>(AB, bias, idxb, n, Hout, act, outbuf);
  };
  auto decoder = [&](const float* xin, float* decout) {
    edge_conv(xin, N_, H_, wcat3, b_mlp3, H_, 2, t1);
    edge_conv(t1,  N_, H_, wcat2, b_mlp2, H_, 2, t2);
    edge_conv(t2,  N_, H_, wcat6, b_mlp6, N_, 0, decout);
  };
  auto gemm = [&](const float* A, const float* W, const float* bias, float* C,
                  int M, int N, int K, int act) {
    dim3 gg(cdiv(N, BN), cdiv(M, BM));
    gemm_kernel<<<gg, 256, 0, stream>>>(A, W, bias, C, M, N, K, act);
  };
  auto sag = [&](const float* h, const float* adj_in, int n, int k,
                 const float* pw, const float* pb,
                 float* top, int* loc, int* perm, float* xpb, float* adjp) {
    int M = B_ * n;
    rowdot_kernel<<<cdiv(M * 64, 256), 256, 0, stream>>>(h, pw, M, H_, nullptr, 0, ybuf);
    gcn_score_kernel<<<B_, 64, 0, stream>>>(adj_in, ybuf, pb, n, sbuf);
    topk_kernel<<<1, 128, 0, stream>>>(sbuf, n, k, top, loc);
    pool_gather_kernel<<<cdiv(B_ * k * H_, 256), 256, 0, stream>>>(h, top, loc, n, k, xpb, perm);
    if (adjp)
      adj_gather_kernel<<<cdiv(B_ * k * k, 256), 256, 0, stream>>>(adj_in, loc, n, k, adjp);
  };

  // ---- precompute ----
  wcat_kernel<<<cdiv(39 * 512, 256), 256, 0, stream>>>(w_mlp1, 39, 256, wcat1);
  wcat_kernel<<<cdiv(256 * 512, 256), 256, 0, stream>>>(w_mlp2, 256, 256, wcat2);
  wcat_kernel<<<cdiv(256 * 512, 256), 256, 0, stream>>>(w_mlp3, 256, 256, wcat3);
  wcat_kernel<<<cdiv(256 * 78, 256), 256, 0, stream>>>(w_mlp6, 256, 39, wcat6);
  degree_kernel<<<cdiv(4992, 256), 256, 0, stream>>>(adj, deg);

  // ---- level 1 ----
  edge_conv(x, N_, N_, wcat1, b_mlp1, H_, 0, t1);                       // pre-BN h1 -> t1
  bn_stats_kernel<<<H_, 256, 0, stream>>>(t1, 4992, stats);
  bn_apply_kernel<<<cdiv(4992 * 256, 256), 256, 0, stream>>>(t1, stats, bn1_g, bn1_b, 4992, hbuf);
  sag(hbuf, adj, N_, K1_, p1_w, p1_b, top1, loc1, perm1, xp, adj1);     // xp1
  hipMemsetAsync(xout, 0, (size_t)4992 * 256 * 4, stream);
  scatter_kernel<<<cdiv(4096 * 256, 256), 256, 0, stream>>>(xp, perm1, nullptr, 4096, xout);
  // degree head (once, from x_out1)
  gemm(xout, lin4_w, lin4_b, t1, 4992, 256, 256, 1);
  gemm(t1, lin5_w, lin5_b, t2, 4992, 128, 256, 1);
  rowdot_kernel<<<cdiv(4992 * 64, 256), 256, 0, stream>>>(t2, lin6_w, 4992, 128, lin6_b, 1, xdeg);
  gtpred_kernel<<<cdiv(4096, 256), 256, 0, stream>>>(deg, xdeg, perm1, 4096, out_gt1, out_pred1);
  readout_kernel<<<cdiv(128 * 256, 256), 256, 0, stream>>>(xp, K1_, 0, z);
  decoder(xout, out_dec1);

  // ---- level 2 ----
  edge_conv(xp, K1_, H_, wcat2, b_mlp2, H_, 0, t1);                     // pre-BN h2 (M=4096)
  bn_stats_kernel<<<H_, 256, 0, stream>>>(t1, 4096, stats);
  bn_apply_kernel<<<cdiv(4096 * 256, 256), 256, 0, stream>>>(t1, stats, bn2_g, bn2_b, 4096, hbuf);
  sag(hbuf, adj1, K1_, K2_, p2_w, p2_b, top2, loc2, perm2, xp, adj2);   // xp2 (overwrites xp)
  hipMemsetAsync(xout, 0, (size_t)4992 * 256 * 4, stream);
  scatter_kernel<<<cdiv(3328 * 256, 256), 256, 0, stream>>>(xp, perm1, perm2, 3328, xout);
  gtpred_kernel<<<cdiv(3328, 256), 256, 0, stream>>>(deg, xdeg, perm2, 3328, out_gt2, out_pred2);
  readout_kernel<<<cdiv(128 * 256, 256), 256, 0, stream>>>(xp, K2_, 1, z);
  decoder(xout, out_dec2);

  // ---- level 3 ----
  edge_conv(xp, K2_, H_, wcat3, b_mlp3, H_, 0, t1);                     // pre-BN h3 (M=3328)
  bn_stats_kernel<<<H_, 256, 0, stream>>>(t1, 3328, stats);
  bn_apply_kernel<<<cdiv(3328 * 256, 256), 256, 0, stream>>>(t1, stats, bn3_g, bn3_b, 3328, hbuf);
  sag(hbuf, adj2, K2_, K3_, p3_w, p3_b, top3, loc3, perm3, xp, nullptr); // xp3; adj3 unused
  hipMemsetAsync(xout, 0, (size_t)4992 * 256 * 4, stream);
  scatter_kernel<<<cdiv(2688 * 256, 256), 256, 0, stream>>>(xp, perm2, perm3, 2688, xout);
  gtpred_kernel<<<cdiv(2688, 256), 256, 0, stream>>>(deg, xdeg, perm3, 2688, out_gt3, out_pred3);
  readout_kernel<<<cdiv(128 * 256, 256), 256, 0, stream>>>(xp, K3_, 1, z);
  decoder(xout, out_dec3);

  // ---- classifier head ----
  gemm(z, lin1_w, lin1_b, z1, 128, 256, 512, 1);
  gemm(z1, lin2_w, lin2_b, z2, 128, 128, 256, 1);
  gemm(z2, lin3_w, lin3_b, logits, 128, 2, 128, 0);
  softmax2_kernel<<<1, 128, 0, stream>>>(logits, out_probs);
}

// Round 2
// 1875.339 us; speedup vs baseline: 1.2148x; 1.2148x over previous
//
#include <hip/hip_runtime.h>
#include <cmath>

#define B_   128
#define N_   39
#define KNN_ 10
#define H_   256
#define K1_  32
#define K2_  26
#define K3_  21

static inline int cdiv(int a, int b) { return (a + b - 1) / b; }

// ---------- wave-wide argmax/argmin (64 lanes), ties -> lowest index ----------
__device__ inline void wave_argmax64(float& v, int& j) {
#pragma unroll
  for (int off = 32; off; off >>= 1) {
    float ov = __shfl_down(v, off, 64);
    int   oj = __shfl_down(j, off, 64);
    if (ov > v || (ov == v && oj < j)) { v = ov; j = oj; }
  }
  v = __shfl(v, 0, 64);
  j = __shfl(j, 0, 64);
}
__device__ inline void wave_argmin64(float& v, int& j) {
#pragma unroll
  for (int off = 32; off; off >>= 1) {
    float ov = __shfl_down(v, off, 64);
    int   oj = __shfl_down(j, off, 64);
    if (ov < v || (ov == v && oj < j)) { v = ov; j = oj; }
  }
  v = __shfl(v, 0, 64);
  j = __shfl(j, 0, 64);
}

// wc[k][c] = c<H ? w_top[k][c]-w_bot[k][c] : w_bot[k][c-H]   (w is (2F,H) row-major)
__global__ void wcat_kernel(const float* __restrict__ w, int F, int Hc, float* __restrict__ wc) {
  int t = blockIdx.x * blockDim.x + threadIdx.x;
  int total = F * 2 * Hc;
  if (t >= total) return;
  int k = t / (2 * Hc);
  int c = t - k * 2 * Hc;
  if (c < Hc) wc[t] = w[k * Hc + c] - w[(F + k) * Hc + c];
  else        wc[t] = w[(F + k) * Hc + (c - Hc)];
}

__global__ void degree_kernel(const float* __restrict__ adj, float* __restrict__ deg) {
  int t = blockIdx.x * blockDim.x + threadIdx.x;
  if (t >= B_ * N_) return;
  const float* row = adj + (size_t)t * N_;
  float s = 0.f;
  for (int j = 0; j < N_; ++j) s += row[j];
  deg[t] = s;
}

// G[b,i,j] = dot(x[b,i], x[b,j])
__global__ void gram_kernel(const float* __restrict__ x, int n, int F, float* __restrict__ G) {
  int t = blockIdx.x * blockDim.x + threadIdx.x;
  if (t >= B_ * n * n) return;
  int b = t / (n * n);
  int r = t - b * n * n;
  int i = r / n;
  int j = r - i * n;
  const float* xi = x + (size_t)(b * n + i) * F;
  const float* xj = x + (size_t)(b * n + j) * F;
  float acc = 0.f;
  if ((F & 3) == 0) {
    const float4* a4 = (const float4*)xi;
    const float4* b4 = (const float4*)xj;
    int F4 = F >> 2;
    for (int f = 0; f < F4; ++f) {
      float4 a = a4[f], bb = b4[f];
      acc += a.x * bb.x + a.y * bb.y + a.z * bb.z + a.w * bb.w;
    }
  } else {
    for (int f = 0; f < F; ++f) acc += xi[f] * xj[f];
  }
  G[t] = acc;
}

// one wave per row i: K nearest (smallest d), ties -> lowest index (stable like lax.top_k)
__global__ void knn_kernel(const float* __restrict__ G, int n, int M, int* __restrict__ idx) {
  int w = (blockIdx.x * blockDim.x + threadIdx.x) >> 6;
  int lane = threadIdx.x & 63;
  if (w >= M) return;
  int b = w / n;
  int i = w - b * n;
  const float* Gb = G + (size_t)b * n * n;
  float d = INFINITY;
  if (lane < n)
    d = Gb[i * n + i] + Gb[lane * n + lane] - 2.f * Gb[i * n + lane];
  int* out = idx + (size_t)w * KNN_;
  float cur = d;
  for (int kk = 0; kk < KNN_; ++kk) {
    float rv = cur;
    int rj = (lane < n) ? lane : (1 << 20);
    wave_argmin64(rv, rj);
    if (lane == 0) out[kk] = rj;
    if (lane == rj) cur = INFINITY;
  }
}

// C = A(MxK) @ W(KxN) [+bias] [relu]; row-major; generic bounds
#define BM 128
#define BN 64
#define BK 16
#define TM 8
#define TN 4
__global__ __launch_bounds__(256) void gemm_kernel(
    const float* __restrict__ A, const float* __restrict__ W, const float* __restrict__ bias,
    float* __restrict__ C, int M, int N, int K, int act) {
  __shared__ float As[BK][BM + 4];
  __shared__ float Bs[BK][BN + 4];
  int tid = threadIdx.x;
  int tx = tid & 15, ty = tid >> 4;       // tx: 16 col-groups of TN, ty: 16 row-groups of TM
  int row0 = blockIdx.y * BM, col0 = blockIdx.x * BN;
  float c[TM][TN] = {};
  for (int k0 = 0; k0 < K; k0 += BK) {
    for (int e = tid; e < BM * BK; e += 256) {
      int m = e >> 4, kk = e & 15;
      int row = row0 + m, k = k0 + kk;
      As[kk][m] = (row < M && k < K) ? A[(size_t)row * K + k] : 0.f;
    }
    for (int e = tid; e < BK * BN; e += 256) {
      int kk = e >> 6, nn = e & 63;
      int k = k0 + kk, col = col0 + nn;
      Bs[kk][nn] = (k < K && col < N) ? W[(size_t)k * N + col] : 0.f;
    }
    __syncthreads();
#pragma unroll
    for (int kk = 0; kk < BK; ++kk) {
      float4 a0 = *(const float4*)&As[kk][ty * TM];
      float4 a1 = *(const float4*)&As[kk][ty * TM + 4];
      float4 bv = *(const float4*)&Bs[kk][tx * TN];
      float a[TM] = {a0.x, a0.y, a0.z, a0.w, a1.x, a1.y, a1.z, a1.w};
      float b[TN] = {bv.x, bv.y, bv.z, bv.w};
#pragma unroll
      for (int i = 0; i < TM; ++i)
#pragma unroll
        for (int j = 0; j < TN; ++j) c[i][j] += a[i] * b[j];
    }
    __syncthreads();
  }
  for (int i = 0; i < TM; ++i) {
    int row = row0 + ty * TM + i;
    if (row >= M) continue;
    for (int j = 0; j < TN; ++j) {
      int col = col0 + tx * TN + j;
      if (col >= N) continue;
      float v = c[i][j] + (bias ? bias[col] : 0.f);
      if (act == 1) v = fmaxf(v, 0.f);
      C[(size_t)row * N + col] = v;
    }
  }
}

// AB row r: [0..Hc) = xi@(Wt-Wb), [Hc..2Hc) = xi@Wb.  out = max_k relu(Ai + b + Bm[nbr]) [tanh]
__global__ void edge_agg_kernel(const float* __restrict__ AB, const float* __restrict__ bias,
                                const int* __restrict__ idx, int n, int Hc, int act,
                                float* __restrict__ out) {
  int t = blockIdx.x * blockDim.x + threadIdx.x;
  if (t >= B_ * n * Hc) return;
  int r = t / Hc, h = t - r * Hc;
  int b = r / n;
  int s2 = 2 * Hc;
  float av = AB[(size_t)r * s2 + h] + bias[h];
  const int* ir = idx + (size_t)r * KNN_;
  int base = b * n;
  float m = -INFINITY;
  for (int k = 0; k < KNN_; ++k) {
    float v = av + AB[(size_t)(base + ir[k]) * s2 + Hc + h];
    v = fmaxf(v, 0.f);
    m = fmaxf(m, v);
  }
  if (act == 2) m = tanhf(m);
  out[t] = m;
}

__global__ void bn_stats_kernel(const float* __restrict__ x, int M, float* __restrict__ mv) {
  int c = blockIdx.x;  // column, H_ blocks
  double s = 0.0, s2 = 0.0;
  for (int r = threadIdx.x; r < M; r += 256) {
    double v = (double)x[(size_t)r * H_ + c];
    s += v; s2 += v * v;
  }
  __shared__ double sh[256], sh2[256];
  sh[threadIdx.x] = s; sh2[threadIdx.x] = s2;
  __syncthreads();
  for (int o = 128; o; o >>= 1) {
    if (threadIdx.x < o) { sh[threadIdx.x] += sh[threadIdx.x + o]; sh2[threadIdx.x] += sh2[threadIdx.x + o]; }
    __syncthreads();
  }
  if (threadIdx.x == 0) {
    double mean = sh[0] / M;
    double var = sh2[0] / M - mean * mean;
    mv[c] = (float)mean;
    mv[H_ + c] = (float)var;
  }
}

__global__ void bn_apply_kernel(const float* __restrict__ x, const float* __restrict__ mv,
                                const float* __restrict__ g, const float* __restrict__ bb,
                                int M, float* __restrict__ out) {
  int t = blockIdx.x * blockDim.x + threadIdx.x;
  if (t >= M * H_) return;
  int h = t & (H_ - 1);
  float mean = mv[h], var = mv[H_ + h];
  float v = (x[t] - mean) * (1.f / sqrtf(var + 1e-5f)) * g[h] + bb[h];
  out[t] = fmaxf(v, 0.f);
}

// one wave per row: y[r] = dot(x[r,:K], w) [+bias] [relu]
__global__ void rowdot_kernel(const float* __restrict__ x, const float* __restrict__ w,
                              int M, int K, const float* __restrict__ bias, int act,
                              float* __restrict__ y) {
  int wid = (blockIdx.x * blockDim.x + threadIdx.x) >> 6;
  int lane = threadIdx.x & 63;
  if (wid >= M) return;
  const float* xr = x + (size_t)wid * K;
  float s = 0.f;
  for (int k = lane; k < K; k += 64) s += xr[k] * w[k];
  for (int off = 32; off; off >>= 1) s += __shfl_down(s, off, 64);
  if (lane == 0) {
    float v = s + (bias ? bias[0] : 0.f);
    if (act == 1) v = fmaxf(v, 0.f);
    y[wid] = v;
  }
}

// s[b,i] = dinv_i * sum_j (adj+I)_ij * dinv_j * y_j + pb ; dinv = rsqrt(rowsum(adj+I))
__global__ void gcn_score_kernel(const float* __restrict__ adj, const float* __restrict__ y,
                                 const float* __restrict__ pb, int n, float* __restrict__ s) {
  int b = blockIdx.x;
  __shared__ float dinv[64], ys[64];
  int i = threadIdx.x;
  if (i < n) {
    const float* ar = adj + ((size_t)b * n + i) * n;
    float sum = 1.f;
    for (int j = 0; j < n; ++j) sum += ar[j];
    dinv[i] = 1.f / sqrtf(sum);
    ys[i] = y[b * n + i];
  }
  __syncthreads();
  if (i < n) {
    const float* ar = adj + ((size_t)b * n + i) * n;
    float acc = 0.f;
    for (int j = 0; j < n; ++j) {
      float a = ar[j] + (i == j ? 1.f : 0.f);
      acc += a * dinv[j] * ys[j];
    }
    s[b * n + i] = dinv[i] * acc + pb[0];
  }
}

// one wave per graph: descending top-k, stable ties (lowest index first)
__global__ void topk_kernel(const float* __restrict__ s, int n, int k,
                            float* __restrict__ top, int* __restrict__ loc) {
  int w = (blockIdx.x * blockDim.x + threadIdx.x) >> 6;
  int lane = threadIdx.x & 63;
  if (w >= B_) return;
  float cur = (lane < n) ? s[w * n + lane] : -INFINITY;
  for (int t = 0; t < k; ++t) {
    float rv = cur;
    int rj = (lane < n) ? lane : (1 << 20);
    wave_argmax64(rv, rj);
    if (lane == 0) { top[w * k + t] = rv; loc[w * k + t] = rj; }
    if (lane == rj) cur = -INFINITY;
  }
}

__global__ void pool_gather_kernel(const float* __restrict__ h, const float* __restrict__ top,
                                   const int* __restrict__ loc, int n, int k,
                                   float* __restrict__ xp, int* __restrict__ perm) {
  int t = blockIdx.x * blockDim.x + threadIdx.x;
  if (t >= B_ * k * H_) return;
  int r = t / H_, hh = t - r * H_;
  int b = r / k;
  int l = loc[r];
  xp[t] = h[((size_t)(b * n + l)) * H_ + hh] * tanhf(top[r]);
  if (hh == 0) perm[r] = b * n + l;
}

__global__ void adj_gather_kernel(const float* __restrict__ adj, const int* __restrict__ loc,
                                  int n, int k, float* __restrict__ adjp) {
  int t = blockIdx.x * blockDim.x + threadIdx.x;
  if (t >= B_ * k * k) return;
  int b = t / (k * k);
  int r = t - b * k * k;
  int t1 = r / k, t2 = r - t1 * k;
  adjp[t] = adj[((size_t)b * n + loc[b * k + t1]) * n + loc[b * k + t2]];
}

// dst[i1[i2[r]] or i1[r]] = src[r]   (dst pre-zeroed)
__global__ void scatter_kernel(const float* __restrict__ src, const int* __restrict__ i1,
                               const int* __restrict__ i2, int rows, float* __restrict__ dst) {
  int t = blockIdx.x * blockDim.x + threadIdx.x;
  if (t >= rows * H_) return;
  int r = t / H_, h = t - r * H_;
  int tgt = i2 ? i1[i2[r]] : i1[r];
  dst[(size_t)tgt * H_ + h] = src[t];
}

__global__ void gtpred_kernel(const float* __restrict__ deg, const float* __restrict__ xdeg,
                              const int* __restrict__ perm, int M,
                              float* __restrict__ gt, float* __restrict__ pred) {
  int t = blockIdx.x * blockDim.x + threadIdx.x;
  if (t >= M) return;
  int p = perm[t];
  gt[t] = deg[p];
  pred[t] = xdeg[p];
}

__global__ void readout_kernel(const float* __restrict__ xp, int k, int acc, float* __restrict__ z) {
  int t = blockIdx.x * blockDim.x + threadIdx.x;
  if (t >= B_ * H_) return;
  int b = t / H_, h = t - b * H_;
  float mx = -INFINITY, sm = 0.f;
  for (int tt = 0; tt < k; ++tt) {
    float v = xp[((size_t)b * k + tt) * H_ + h];
    mx = fmaxf(mx, v);
    sm += v;
  }
  float* zb = z + (size_t)b * 2 * H_;
  float mean = sm / (float)k;
  if (acc) { zb[h] += mx; zb[H_ + h] += mean; }
  else     { zb[h] = mx;  zb[H_ + h] = mean; }
}

__global__ void softmax2_kernel(const float* __restrict__ logits, float* __restrict__ probs) {
  int b = blockIdx.x * blockDim.x + threadIdx.x;
  if (b >= B_) return;
  float a = logits[2 * b], c = logits[2 * b + 1];
  float m = fmaxf(a, c);
  float ea = expf(a - m), ec = expf(c - m);
  float inv = 1.f / (ea + ec);
  probs[2 * b] = ea * inv;
  probs[2 * b + 1] = ec * inv;
}

extern "C" void kernel_launch(void* const* d_in, const int* in_sizes, int n_in,
                              void* d_out, int out_size, void* d_ws, size_t ws_size,
                              hipStream_t stream) {
  auto in = [&](int i) { return (const float*)d_in[i]; };
  const float* x      = in(0);
  const float* adj    = in(1);
  const float* w_mlp1 = in(2);  const float* b_mlp1 = in(3);
  const float* w_mlp2 = in(4);  const float* b_mlp2 = in(5);
  const float* w_mlp3 = in(6);  const float* b_mlp3 = in(7);
  const float* w_mlp6 = in(8);  const float* b_mlp6 = in(9);
  const float* bn1_g = in(10);  const float* bn1_b = in(11);
  const float* bn2_g = in(12);  const float* bn2_b = in(13);
  const float* bn3_g = in(14);  const float* bn3_b = in(15);
  const float* p1_w = in(16);   const float* p1_b = in(17);
  const float* p2_w = in(18);   const float* p2_b = in(19);
  const float* p3_w = in(20);   const float* p3_b = in(21);
  const float* lin1_w = in(22); const float* lin1_b = in(23);
  const float* lin2_w = in(24); const float* lin2_b = in(25);
  const float* lin3_w = in(26); const float* lin3_b = in(27);
  const float* lin4_w = in(28); const float* lin4_b = in(29);
  const float* lin5_w = in(30); const float* lin5_b = in(31);
  const float* lin6_w = in(32); const float* lin6_b = in(33);

  float* out = (float*)d_out;
  float* out_probs = out;                      // 128*2
  float* out_dec1  = out_probs + 256;          // 4992*39
  float* out_dec2  = out_dec1 + 4992 * 39;
  float* out_dec3  = out_dec2 + 4992 * 39;
  float* out_gt1   = out_dec3 + 4992 * 39;     // 4096
  float* out_pred1 = out_gt1 + 4096;           // 4096
  float* out_gt2   = out_pred1 + 4096;         // 3328
  float* out_pred2 = out_gt2 + 3328;
  float* out_gt3   = out_pred2 + 3328;         // 2688
  float* out_pred3 = out_gt3 + 2688;

  char* base = (char*)d_ws;
  size_t off = 0;
  auto allocf = [&](size_t n) -> float* {
    float* p = (float*)(base + off);
    off += ((n * sizeof(float) + 255) & ~(size_t)255);
    return p;
  };
  auto alloci = [&](size_t n) -> int* {
    int* p = (int*)(base + off);
    off += ((n * sizeof(int) + 255) & ~(size_t)255);
    return p;
  };

  float* wcat1 = allocf(39 * 512);
  float* wcat2 = allocf(256 * 512);
  float* wcat3 = allocf(256 * 512);
  float* wcat6 = allocf(256 * 78);
  float* deg   = allocf(4992);
  float* xdeg  = allocf(4992);
  float* ybuf  = allocf(4992);
  float* sbuf  = allocf(4992);
  float* stats = allocf(512);
  float* G     = allocf(128 * 39 * 39);
  int*   idxb  = alloci(4992 * KNN_);
  float* AB    = allocf((size_t)4992 * 512);
  float* t1    = allocf((size_t)4992 * 256);
  float* t2    = allocf((size_t)4992 * 256);
  float* hbuf  = allocf((size_t)4992 * 256);
  float* xp    = allocf((size_t)4096 * 256);
  float* xout  = allocf((size_t)4992 * 256);
  float* adj1  = allocf(128 * 32 * 32);
  float* adj2  = allocf(128 * 26 * 26);
  float* top1  = allocf(4096);
  float* top2  = allocf(3328);
  float* top3  = allocf(2688);
  int* loc1 = alloci(4096); int* loc2 = alloci(3328); int* loc3 = alloci(2688);
  int* perm1 = alloci(4096); int* perm2 = alloci(3328); int* perm3 = alloci(2688);
  float* z  = allocf(128 * 512);
  float* z1 = allocf(128 * 256);
  float* z2 = allocf(128 * 128);
  float* logits = allocf(256);
  if (off > ws_size) return;  // workspace too small — fail loudly via poisoned output

  auto edge_conv = [&](const float* xin, int n, int F, const float* wcat, const float* bias,
                       int Hout, int act, float* outbuf) {
    int M = B_ * n;
    gram_kernel<<<cdiv(B_ * n * n, 256), 256, 0, stream>>>(xin, n, F, G);
    knn_kernel<<<cdiv(M * 64, 256), 256, 0, stream>>>(G, n, M, idxb);
    dim3 gg(cdiv(2 * Hout, BN), cdiv(M, BM));
    gemm_kernel<<<gg, 256, 0, stream>>>(xin, wcat, nullptr, AB, M, 2 * Hout, F, 0);
    edge_agg_kernel<<<cdiv(M * Hout, 256), 256, 0, stream>>>(AB, bias, idxb, n, Hout, act, outbuf);
  };
  auto decoder = [&](const float* xin, float* decout) {
    edge_conv(xin, N_, H_, wcat3, b_mlp3, H_, 2, t1);
    edge_conv(t1,  N_, H_, wcat2, b_mlp2, H_, 2, t2);
    edge_conv(t2,  N_, H_, wcat6, b_mlp6, N_, 0, decout);
  };
  auto gemm = [&](const float* A, const float* W, const float* bias, float* C,
                  int M, int N, int K, int act) {
    dim3 gg(cdiv(N, BN), cdiv(M, BM));
    gemm_kernel<<<gg, 256, 0, stream>>>(A, W, bias, C, M, N, K, act);
  };
  auto sag = [&](const float* h, const float* adj_in, int n, int k,
                 const float* pw, const float* pb,
                 float* top, int* loc, int* perm, float* xpb, float* adjp) {
    int M = B_ * n;
    rowdot_kernel<<<cdiv(M * 64, 256), 256, 0, stream>>>(h, pw, M, H_, nullptr, 0, ybuf);
    gcn_score_kernel<<<B_, 64, 0, stream>>>(adj_in, ybuf, pb, n, sbuf);
    topk_kernel<<<cdiv(B_ * 64, 256), 256, 0, stream>>>(sbuf, n, k, top, loc);
    pool_gather_kernel<<<cdiv(B_ * k * H_, 256), 256, 0, stream>>>(h, top, loc, n, k, xpb, perm);
    if (adjp)
      adj_gather_kernel<<<cdiv(B_ * k * k, 256), 256, 0, stream>>>(adj_in, loc, n, k, adjp);
  };

  // ---- precompute ----
  wcat_kernel<<<cdiv(39 * 512, 256), 256, 0, stream>>>(w_mlp1, 39, 256, wcat1);
  wcat_kernel<<<cdiv(256 * 512, 256), 256, 0, stream>>>(w_mlp2, 256, 256, wcat2);
  wcat_kernel<<<cdiv(256 * 512, 256), 256, 0, stream>>>(w_mlp3, 256, 256, wcat3);
  wcat_kernel<<<cdiv(256 * 78, 256), 256, 0, stream>>>(w_mlp6, 256, 39, wcat6);
  degree_kernel<<<cdiv(4992, 256), 256, 0, stream>>>(adj, deg);

  // ---- level 1 ----
  edge_conv(x, N_, N_, wcat1, b_mlp1, H_, 0, t1);                       // pre-BN h1 -> t1
  bn_stats_kernel<<<H_, 256, 0, stream>>>(t1, 4992, stats);
  bn_apply_kernel<<<cdiv(4992 * 256, 256), 256, 0, stream>>>(t1, stats, bn1_g, bn1_b, 4992, hbuf);
  sag(hbuf, adj, N_, K1_, p1_w, p1_b, top1, loc1, perm1, xp, adj1);     // xp1
  hipMemsetAsync(xout, 0, (size_t)4992 * 256 * 4, stream);
  scatter_kernel<<<cdiv(4096 * 256, 256), 256, 0, stream>>>(xp, perm1, nullptr, 4096, xout);
  // degree head (once, from x_out1)
  gemm(xout, lin4_w, lin4_b, t1, 4992, 256, 256, 1);
  gemm(t1, lin5_w, lin5_b, t2, 4992, 128, 256, 1);
  rowdot_kernel<<<cdiv(4992 * 64, 256), 256, 0, stream>>>(t2, lin6_w, 4992, 128, lin6_b, 1, xdeg);
  gtpred_kernel<<<cdiv(4096, 256), 256, 0, stream>>>(deg, xdeg, perm1, 4096, out_gt1, out_pred1);
  readout_kernel<<<cdiv(128 * 256, 256), 256, 0, stream>>>(xp, K1_, 0, z);
  decoder(xout, out_dec1);

  // ---- level 2 ----
  edge_conv(xp, K1_, H_, wcat2, b_mlp2, H_, 0, t1);                     // pre-BN h2 (M=4096)
  bn_stats_kernel<<<H_, 256, 0, stream>>>(t1, 4096, stats);
  bn_apply_kernel<<<cdiv(4096 * 256, 256), 256, 0, stream>>>(t1, stats, bn2_g, bn2_b, 4096, hbuf);
  sag(hbuf, adj1, K1_, K2_, p2_w, p2_b, top2, loc2, perm2, xp, adj2);   // xp2 (overwrites xp)
  hipMemsetAsync(xout, 0, (size_t)4992 * 256 * 4, stream);
  scatter_kernel<<<cdiv(3328 * 256, 256), 256, 0, stream>>>(xp, perm1, perm2, 3328, xout);
  gtpred_kernel<<<cdiv(3328, 256), 256, 0, stream>>>(deg, xdeg, perm2, 3328, out_gt2, out_pred2);
  readout_kernel<<<cdiv(128 * 256, 256), 256, 0, stream>>>(xp, K2_, 1, z);
  decoder(xout, out_dec2);

  // ---- level 3 ----
  edge_conv(xp, K2_, H_, wcat3, b_mlp3, H_, 0, t1);                     // pre-BN h3 (M=3328)
  bn_stats_kernel<<<H_, 256, 0, stream>>>(t1, 3328, stats);
  bn_apply_kernel<<<cdiv(3328 * 256, 256), 256, 0, stream>>>(t1, stats, bn3_g, bn3_b, 3328, hbuf);
  sag(hbuf, adj2, K2_, K3_, p3_w, p3_b, top3, loc3, perm3, xp, nullptr); // xp3; adj3 unused
  hipMemsetAsync(xout, 0, (size_t)4992 * 256 * 4, stream);
  scatter_kernel<<<cdiv(2688 * 256, 256), 256, 0, stream>>>(xp, perm2, perm3, 2688, xout);
  gtpred_kernel<<<cdiv(2688, 256), 256, 0, stream>>>(deg, xdeg, perm3, 2688, out_gt3, out_pred3);
  readout_kernel<<<cdiv(128 * 256, 256), 256, 0, stream>>>(xp, K3_, 1, z);
  decoder(xout, out_dec3);

  // ---- classifier head ----
  gemm(z, lin1_w, lin1_b, z1, 128, 256, 512, 1);
  gemm(z1, lin2_w, lin2_b, z2, 128, 128, 256, 1);
  gemm(z2, lin3_w, lin3_b, logits, 128, 2, 128, 0);
  softmax2_kernel<<<1, 128, 0, stream>>>(logits, out_probs);
}

// Round 3
// 1735.280 us; speedup vs baseline: 1.3128x; 1.0807x over previous
//
#include <hip/hip_runtime.h>
#include <cmath>

#define B_   128
#define N_   39
#define KNN_ 10
#define H_   256
#define K1_  32
#define K2_  26
#define K3_  21

static inline int cdiv(int a, int b) { return (a + b - 1) / b; }

// ---------- wave-wide argmax/argmin (64 lanes), ties -> lowest index ----------
__device__ inline void wave_argmax64(float& v, int& j) {
#pragma unroll
  for (int off = 32; off; off >>= 1) {
    float ov = __shfl_down(v, off, 64);
    int   oj = __shfl_down(j, off, 64);
    if (ov > v || (ov == v && oj < j)) { v = ov; j = oj; }
  }
  v = __shfl(v, 0, 64);
  j = __shfl(j, 0, 64);
}
__device__ inline void wave_argmin64(float& v, int& j) {
#pragma unroll
  for (int off = 32; off; off >>= 1) {
    float ov = __shfl_down(v, off, 64);
    int   oj = __shfl_down(j, off, 64);
    if (ov < v || (ov == v && oj < j)) { v = ov; j = oj; }
  }
  v = __shfl(v, 0, 64);
  j = __shfl(j, 0, 64);
}

// wc[k][c] = c<H ? w_top[k][c]-w_bot[k][c] : w_bot[k][c-H]   (w is (2F,H) row-major)
__global__ void wcat_kernel(const float* __restrict__ w, int F, int Hc, float* __restrict__ wc) {
  int t = blockIdx.x * blockDim.x + threadIdx.x;
  int total = F * 2 * Hc;
  if (t >= total) return;
  int k = t / (2 * Hc);
  int c = t - k * 2 * Hc;
  if (c < Hc) wc[t] = w[k * Hc + c] - w[(F + k) * Hc + c];
  else        wc[t] = w[(F + k) * Hc + (c - Hc)];
}

__global__ void degree_kernel(const float* __restrict__ adj, float* __restrict__ deg) {
  int t = blockIdx.x * blockDim.x + threadIdx.x;
  if (t >= B_ * N_) return;
  const float* row = adj + (size_t)t * N_;
  float s = 0.f;
  for (int j = 0; j < N_; ++j) s += row[j];
  deg[t] = s;
}

// Block-per-graph Gram: G[b,i,j] = dot(x[b,i], x[b,j]); x[b] staged in LDS,
// rows padded/zeroed to 40 so the 2x4 register tile needs no load guards.
__global__ __launch_bounds__(256) void gram_kernel(const float* __restrict__ x, int n, int F,
                                                   float* __restrict__ G) {
  __shared__ float xs[40 * 256];
  int b = blockIdx.x;
  const float* xb = x + (size_t)b * n * F;
  int total = n * F;
  for (int t = threadIdx.x; t < total; t += 256) xs[t] = xb[t];
  for (int t = total + threadIdx.x; t < 40 * F; t += 256) xs[t] = 0.f;
  __syncthreads();
  int rtiles = (n + 1) >> 1;   // rows of 2
  int ctiles = (n + 3) >> 2;   // cols of 4
  float* Gb = G + (size_t)b * n * n;
  for (int t = threadIdx.x; t < rtiles * ctiles; t += 256) {
    int rt = t / ctiles, ct = t - rt * ctiles;
    int i0 = rt * 2, j0 = ct * 4;
    float acc[2][4] = {};
    if ((F & 3) == 0) {
      for (int f = 0; f < F; f += 4) {
        float4 a0 = *(const float4*)&xs[i0 * F + f];
        float4 a1 = *(const float4*)&xs[(i0 + 1) * F + f];
#pragma unroll
        for (int j = 0; j < 4; ++j) {
          float4 bv = *(const float4*)&xs[(j0 + j) * F + f];
          acc[0][j] += a0.x * bv.x + a0.y * bv.y + a0.z * bv.z + a0.w * bv.w;
          acc[1][j] += a1.x * bv.x + a1.y * bv.y + a1.z * bv.z + a1.w * bv.w;
        }
      }
    } else {
      for (int f = 0; f < F; ++f) {
        float a0 = xs[i0 * F + f], a1 = xs[(i0 + 1) * F + f];
#pragma unroll
        for (int j = 0; j < 4; ++j) {
          float bv = xs[(j0 + j) * F + f];
          acc[0][j] += a0 * bv;
          acc[1][j] += a1 * bv;
        }
      }
    }
#pragma unroll
    for (int i = 0; i < 2; ++i) {
      if (i0 + i >= n) continue;
#pragma unroll
      for (int j = 0; j < 4; ++j) {
        if (j0 + j >= n) continue;
        Gb[(i0 + i) * n + (j0 + j)] = acc[i][j];
      }
    }
  }
}

// one wave per row i: K nearest (smallest d), ties -> lowest index (stable like lax.top_k)
__global__ void knn_kernel(const float* __restrict__ G, int n, int M, int* __restrict__ idx) {
  int w = (blockIdx.x * blockDim.x + threadIdx.x) >> 6;
  int lane = threadIdx.x & 63;
  if (w >= M) return;
  int b = w / n;
  int i = w - b * n;
  const float* Gb = G + (size_t)b * n * n;
  float d = INFINITY;
  if (lane < n)
    d = Gb[i * n + i] + Gb[lane * n + lane] - 2.f * Gb[i * n + lane];
  int* out = idx + (size_t)w * KNN_;
  float cur = d;
  for (int kk = 0; kk < KNN_; ++kk) {
    float rv = cur;
    int rj = (lane < n) ? lane : (1 << 20);
    wave_argmin64(rv, rj);
    if (lane == 0) out[kk] = rj;
    if (lane == rj) cur = INFINITY;
  }
}

// C = A(MxK) @ W(KxN) [+bias] [relu]; row-major; generic bounds
#define BM 128
#define BN 64
#define BK 16
#define TM 8
#define TN 4
__global__ __launch_bounds__(256) void gemm_kernel(
    const float* __restrict__ A, const float* __restrict__ W, const float* __restrict__ bias,
    float* __restrict__ C, int M, int N, int K, int act) {
  __shared__ float As[BK][BM + 4];
  __shared__ float Bs[BK][BN + 4];
  int tid = threadIdx.x;
  int tx = tid & 15, ty = tid >> 4;       // tx: 16 col-groups of TN, ty: 16 row-groups of TM
  int row0 = blockIdx.y * BM, col0 = blockIdx.x * BN;
  float c[TM][TN] = {};
  for (int k0 = 0; k0 < K; k0 += BK) {
    for (int e = tid; e < BM * BK; e += 256) {
      int m = e >> 4, kk = e & 15;
      int row = row0 + m, k = k0 + kk;
      As[kk][m] = (row < M && k < K) ? A[(size_t)row * K + k] : 0.f;
    }
    for (int e = tid; e < BK * BN; e += 256) {
      int kk = e >> 6, nn = e & 63;
      int k = k0 + kk, col = col0 + nn;
      Bs[kk][nn] = (k < K && col < N) ? W[(size_t)k * N + col] : 0.f;
    }
    __syncthreads();
#pragma unroll
    for (int kk = 0; kk < BK; ++kk) {
      float4 a0 = *(const float4*)&As[kk][ty * TM];
      float4 a1 = *(const float4*)&As[kk][ty * TM + 4];
      float4 bv = *(const float4*)&Bs[kk][tx * TN];
      float a[TM] = {a0.x, a0.y, a0.z, a0.w, a1.x, a1.y, a1.z, a1.w};
      float b[TN] = {bv.x, bv.y, bv.z, bv.w};
#pragma unroll
      for (int i = 0; i < TM; ++i)
#pragma unroll
        for (int j = 0; j < TN; ++j) c[i][j] += a[i] * b[j];
    }
    __syncthreads();
  }
  for (int i = 0; i < TM; ++i) {
    int row = row0 + ty * TM + i;
    if (row >= M) continue;
    for (int j = 0; j < TN; ++j) {
      int col = col0 + tx * TN + j;
      if (col >= N) continue;
      float v = c[i][j] + (bias ? bias[col] : 0.f);
      if (act == 1) v = fmaxf(v, 0.f);
      C[(size_t)row * N + col] = v;
    }
  }
}

// Thin GEMM (small M): one block per row. A row staged in LDS; threads sweep cols
// with coalesced W loads. K <= 512.
__global__ __launch_bounds__(256) void rowgemm_kernel(
    const float* __restrict__ A, const float* __restrict__ W, const float* __restrict__ bias,
    float* __restrict__ C, int N, int K, int act) {
  __shared__ float a[512];
  int row = blockIdx.x;
  for (int k = threadIdx.x; k < K; k += 256) a[k] = A[(size_t)row * K + k];
  __syncthreads();
  for (int c = threadIdx.x; c < N; c += 256) {
    float s = 0.f;
    for (int k = 0; k < K; k += 4) {
      float4 av = *(const float4*)&a[k];
      s += av.x * W[(size_t)k * N + c];
      s += av.y * W[(size_t)(k + 1) * N + c];
      s += av.z * W[(size_t)(k + 2) * N + c];
      s += av.w * W[(size_t)(k + 3) * N + c];
    }
    float v = s + (bias ? bias[c] : 0.f);
    if (act == 1) v = fmaxf(v, 0.f);
    C[(size_t)row * N + c] = v;
  }
}

// one wave per output element (for very small M*N)
__global__ void wavedot_gemm_kernel(const float* __restrict__ A, const float* __restrict__ W,
                                    const float* __restrict__ bias, float* __restrict__ C,
                                    int M, int N, int K, int act) {
  int wid = (blockIdx.x * blockDim.x + threadIdx.x) >> 6;
  int lane = threadIdx.x & 63;
  if (wid >= M * N) return;
  int row = wid / N, col = wid - row * N;
  const float* ar = A + (size_t)row * K;
  float s = 0.f;
  for (int k = lane; k < K; k += 64) s += ar[k] * W[(size_t)k * N + col];
  for (int off = 32; off; off >>= 1) s += __shfl_down(s, off, 64);
  if (lane == 0) {
    float v = s + (bias ? bias[col] : 0.f);
    if (act == 1) v = fmaxf(v, 0.f);
    C[(size_t)row * N + col] = v;
  }
}

// AB row r: [0..Hc) = xi@(Wt-Wb), [Hc..2Hc) = xi@Wb.  out = max_k relu(Ai + b + Bm[nbr]) [tanh]
__global__ void edge_agg_kernel(const float* __restrict__ AB, const float* __restrict__ bias,
                                const int* __restrict__ idx, int n, int Hc, int act,
                                float* __restrict__ out) {
  int t = blockIdx.x * blockDim.x + threadIdx.x;
  if (t >= B_ * n * Hc) return;
  int r = t / Hc, h = t - r * Hc;
  int b = r / n;
  int s2 = 2 * Hc;
  float av = AB[(size_t)r * s2 + h] + bias[h];
  const int* ir = idx + (size_t)r * KNN_;
  int base = b * n;
  float m = -INFINITY;
  for (int k = 0; k < KNN_; ++k) {
    float v = av + AB[(size_t)(base + ir[k]) * s2 + Hc + h];
    v = fmaxf(v, 0.f);
    m = fmaxf(m, v);
  }
  if (act == 2) m = tanhf(m);
  out[t] = m;
}

__global__ void bn_stats_kernel(const float* __restrict__ x, int M, float* __restrict__ mv) {
  int c = blockIdx.x;  // column, H_ blocks
  double s = 0.0, s2 = 0.0;
  for (int r = threadIdx.x; r < M; r += 256) {
    double v = (double)x[(size_t)r * H_ + c];
    s += v; s2 += v * v;
  }
  __shared__ double sh[256], sh2[256];
  sh[threadIdx.x] = s; sh2[threadIdx.x] = s2;
  __syncthreads();
  for (int o = 128; o; o >>= 1) {
    if (threadIdx.x < o) { sh[threadIdx.x] += sh[threadIdx.x + o]; sh2[threadIdx.x] += sh2[threadIdx.x + o]; }
    __syncthreads();
  }
  if (threadIdx.x == 0) {
    double mean = sh[0] / M;
    double var = sh2[0] / M - mean * mean;
    mv[c] = (float)mean;
    mv[H_ + c] = (float)var;
  }
}

__global__ void bn_apply_kernel(const float* __restrict__ x, const float* __restrict__ mv,
                                const float* __restrict__ g, const float* __restrict__ bb,
                                int M, float* __restrict__ out) {
  int t = blockIdx.x * blockDim.x + threadIdx.x;
  if (t >= M * H_) return;
  int h = t & (H_ - 1);
  float mean = mv[h], var = mv[H_ + h];
  float v = (x[t] - mean) * (1.f / sqrtf(var + 1e-5f)) * g[h] + bb[h];
  out[t] = fmaxf(v, 0.f);
}

// one wave per row: y[r] = dot(x[r,:K], w) [+bias] [relu]
__global__ void rowdot_kernel(const float* __restrict__ x, const float* __restrict__ w,
                              int M, int K, const float* __restrict__ bias, int act,
                              float* __restrict__ y) {
  int wid = (blockIdx.x * blockDim.x + threadIdx.x) >> 6;
  int lane = threadIdx.x & 63;
  if (wid >= M) return;
  const float* xr = x + (size_t)wid * K;
  float s = 0.f;
  for (int k = lane; k < K; k += 64) s += xr[k] * w[k];
  for (int off = 32; off; off >>= 1) s += __shfl_down(s, off, 64);
  if (lane == 0) {
    float v = s + (bias ? bias[0] : 0.f);
    if (act == 1) v = fmaxf(v, 0.f);
    y[wid] = v;
  }
}

// s[b,i] = dinv_i * sum_j (adj+I)_ij * dinv_j * y_j + pb ; dinv = rsqrt(rowsum(adj+I))
__global__ void gcn_score_kernel(const float* __restrict__ adj, const float* __restrict__ y,
                                 const float* __restrict__ pb, int n, float* __restrict__ s) {
  int b = blockIdx.x;
  __shared__ float dinv[64], ys[64];
  int i = threadIdx.x;
  if (i < n) {
    const float* ar = adj + ((size_t)b * n + i) * n;
    float sum = 1.f;
    for (int j = 0; j < n; ++j) sum += ar[j];
    dinv[i] = 1.f / sqrtf(sum);
    ys[i] = y[b * n + i];
  }
  __syncthreads();
  if (i < n) {
    const float* ar = adj + ((size_t)b * n + i) * n;
    float acc = 0.f;
    for (int j = 0; j < n; ++j) {
      float a = ar[j] + (i == j ? 1.f : 0.f);
      acc += a * dinv[j] * ys[j];
    }
    s[b * n + i] = dinv[i] * acc + pb[0];
  }
}

// one wave per graph: descending top-k, stable ties (lowest index first)
__global__ void topk_kernel(const float* __restrict__ s, int n, int k,
                            float* __restrict__ top, int* __restrict__ loc) {
  int w = (blockIdx.x * blockDim.x + threadIdx.x) >> 6;
  int lane = threadIdx.x & 63;
  if (w >= B_) return;
  float cur = (lane < n) ? s[w * n + lane] : -INFINITY;
  for (int t = 0; t < k; ++t) {
    float rv = cur;
    int rj = (lane < n) ? lane : (1 << 20);
    wave_argmax64(rv, rj);
    if (lane == 0) { top[w * k + t] = rv; loc[w * k + t] = rj; }
    if (lane == rj) cur = -INFINITY;
  }
}

__global__ void pool_gather_kernel(const float* __restrict__ h, const float* __restrict__ top,
                                   const int* __restrict__ loc, int n, int k,
                                   float* __restrict__ xp, int* __restrict__ perm) {
  int t = blockIdx.x * blockDim.x + threadIdx.x;
  if (t >= B_ * k * H_) return;
  int r = t / H_, hh = t - r * H_;
  int b = r / k;
  int l = loc[r];
  xp[t] = h[((size_t)(b * n + l)) * H_ + hh] * tanhf(top[r]);
  if (hh == 0) perm[r] = b * n + l;
}

__global__ void adj_gather_kernel(const float* __restrict__ adj, const int* __restrict__ loc,
                                  int n, int k, float* __restrict__ adjp) {
  int t = blockIdx.x * blockDim.x + threadIdx.x;
  if (t >= B_ * k * k) return;
  int b = t / (k * k);
  int r = t - b * k * k;
  int t1 = r / k, t2 = r - t1 * k;
  adjp[t] = adj[((size_t)b * n + loc[b * k + t1]) * n + loc[b * k + t2]];
}

// dst[i1[i2[r]] or i1[r]] = src[r]   (dst pre-zeroed)
__global__ void scatter_kernel(const float* __restrict__ src, const int* __restrict__ i1,
                               const int* __restrict__ i2, int rows, float* __restrict__ dst) {
  int t = blockIdx.x * blockDim.x + threadIdx.x;
  if (t >= rows * H_) return;
  int r = t / H_, h = t - r * H_;
  int tgt = i2 ? i1[i2[r]] : i1[r];
  dst[(size_t)tgt * H_ + h] = src[t];
}

__global__ void gtpred_kernel(const float* __restrict__ deg, const float* __restrict__ xdeg,
                              const int* __restrict__ perm, int M,
                              float* __restrict__ gt, float* __restrict__ pred) {
  int t = blockIdx.x * blockDim.x + threadIdx.x;
  if (t >= M) return;
  int p = perm[t];
  gt[t] = deg[p];
  pred[t] = xdeg[p];
}

__global__ void readout_kernel(const float* __restrict__ xp, int k, int acc, float* __restrict__ z) {
  int t = blockIdx.x * blockDim.x + threadIdx.x;
  if (t >= B_ * H_) return;
  int b = t / H_, h = t - b * H_;
  float mx = -INFINITY, sm = 0.f;
  for (int tt = 0; tt < k; ++tt) {
    float v = xp[((size_t)b * k + tt) * H_ + h];
    mx = fmaxf(mx, v);
    sm += v;
  }
  float* zb = z + (size_t)b * 2 * H_;
  float mean = sm / (float)k;
  if (acc) { zb[h] += mx; zb[H_ + h] += mean; }
  else     { zb[h] = mx;  zb[H_ + h] = mean; }
}

__global__ void softmax2_kernel(const float* __restrict__ logits, float* __restrict__ probs) {
  int b = blockIdx.x * blockDim.x + threadIdx.x;
  if (b >= B_) return;
  float a = logits[2 * b], c = logits[2 * b + 1];
  float m = fmaxf(a, c);
  float ea = expf(a - m), ec = expf(c - m);
  float inv = 1.f / (ea + ec);
  probs[2 * b] = ea * inv;
  probs[2 * b + 1] = ec * inv;
}

extern "C" void kernel_launch(void* const* d_in, const int* in_sizes, int n_in,
                              void* d_out, int out_size, void* d_ws, size_t ws_size,
                              hipStream_t stream) {
  auto in = [&](int i) { return (const float*)d_in[i]; };
  const float* x      = in(0);
  const float* adj    = in(1);
  const float* w_mlp1 = in(2);  const float* b_mlp1 = in(3);
  const float* w_mlp2 = in(4);  const float* b_mlp2 = in(5);
  const float* w_mlp3 = in(6);  const float* b_mlp3 = in(7);
  const float* w_mlp6 = in(8);  const float* b_mlp6 = in(9);
  const float* bn1_g = in(10);  const float* bn1_b = in(11);
  const float* bn2_g = in(12);  const float* bn2_b = in(13);
  const float* bn3_g = in(14);  const float* bn3_b = in(15);
  const float* p1_w = in(16);   const float* p1_b = in(17);
  const float* p2_w = in(18);   const float* p2_b = in(19);
  const float* p3_w = in(20);   const float* p3_b = in(21);
  const float* lin1_w = in(22); const float* lin1_b = in(23);
  const float* lin2_w = in(24); const float* lin2_b = in(25);
  const float* lin3_w = in(26); const float* lin3_b = in(27);
  const float* lin4_w = in(28); const float* lin4_b = in(29);
  const float* lin5_w = in(30); const float* lin5_b = in(31);
  const float* lin6_w = in(32); const float* lin6_b = in(33);

  float* out = (float*)d_out;
  float* out_probs = out;                      // 128*2
  float* out_dec1  = out_probs + 256;          // 4992*39
  float* out_dec2  = out_dec1 + 4992 * 39;
  float* out_dec3  = out_dec2 + 4992 * 39;
  float* out_gt1   = out_dec3 + 4992 * 39;     // 4096
  float* out_pred1 = out_gt1 + 4096;           // 4096
  float* out_gt2   = out_pred1 + 4096;         // 3328
  float* out_pred2 = out_gt2 + 3328;
  float* out_gt3   = out_pred2 + 3328;         // 2688
  float* out_pred3 = out_gt3 + 2688;

  char* base = (char*)d_ws;
  size_t off = 0;
  auto allocf = [&](size_t n) -> float* {
    float* p = (float*)(base + off);
    off += ((n * sizeof(float) + 255) & ~(size_t)255);
    return p;
  };
  auto alloci = [&](size_t n) -> int* {
    int* p = (int*)(base + off);
    off += ((n * sizeof(int) + 255) & ~(size_t)255);
    return p;
  };

  float* wcat1 = allocf(39 * 512);
  float* wcat2 = allocf(256 * 512);
  float* wcat3 = allocf(256 * 512);
  float* wcat6 = allocf(256 * 78);
  float* deg   = allocf(4992);
  float* xdeg  = allocf(4992);
  float* ybuf  = allocf(4992);
  float* sbuf  = allocf(4992);
  float* stats = allocf(512);
  float* G     = allocf(128 * 39 * 39);
  int*   idxb  = alloci(4992 * KNN_);
  float* AB    = allocf((size_t)4992 * 512);
  float* t1    = allocf((size_t)4992 * 256);
  float* t2    = allocf((size_t)4992 * 256);
  float* hbuf  = allocf((size_t)4992 * 256);
  float* xp    = allocf((size_t)4096 * 256);
  float* xout  = allocf((size_t)4992 * 256);
  float* adj1  = allocf(128 * 32 * 32);
  float* adj2  = allocf(128 * 26 * 26);
  float* top1  = allocf(4096);
  float* top2  = allocf(3328);
  float* top3  = allocf(2688);
  int* loc1 = alloci(4096); int* loc2 = alloci(3328); int* loc3 = alloci(2688);
  int* perm1 = alloci(4096); int* perm2 = alloci(3328); int* perm3 = alloci(2688);
  float* z  = allocf(128 * 512);
  float* z1 = allocf(128 * 256);
  float* z2 = allocf(128 * 128);
  float* logits = allocf(256);
  if (off > ws_size) return;  // workspace too small — fail loudly via poisoned output

  auto edge_conv = [&](const float* xin, int n, int F, const float* wcat, const float* bias,
                       int Hout, int act, float* outbuf) {
    int M = B_ * n;
    gram_kernel<<<B_, 256, 0, stream>>>(xin, n, F, G);
    knn_kernel<<<cdiv(M * 64, 256), 256, 0, stream>>>(G, n, M, idxb);
    dim3 gg(cdiv(2 * Hout, BN), cdiv(M, BM));
    gemm_kernel<<<gg, 256, 0, stream>>>(xin, wcat, nullptr, AB, M, 2 * Hout, F, 0);
    edge_agg_kernel<<<cdiv(M * Hout, 256), 256, 0, stream>>>(AB, bias, idxb, n, Hout, act, outbuf);
  };
  auto decoder = [&](const float* xin, float* decout) {
    edge_conv(xin, N_, H_, wcat3, b_mlp3, H_, 2, t1);
    edge_conv(t1,  N_, H_, wcat2, b_mlp2, H_, 2, t2);
    edge_conv(t2,  N_, H_, wcat6, b_mlp6, N_, 0, decout);
  };
  auto gemm = [&](const float* A, const float* W, const float* bias, float* C,
                  int M, int N, int K, int act) {
    dim3 gg(cdiv(N, BN), cdiv(M, BM));
    gemm_kernel<<<gg, 256, 0, stream>>>(A, W, bias, C, M, N, K, act);
  };
  auto sag = [&](const float* h, const float* adj_in, int n, int k,
                 const float* pw, const float* pb,
                 float* top, int* loc, int* perm, float* xpb, float* adjp) {
    int M = B_ * n;
    rowdot_kernel<<<cdiv(M * 64, 256), 256, 0, stream>>>(h, pw, M, H_, nullptr, 0, ybuf);
    gcn_score_kernel<<<B_, 64, 0, stream>>>(adj_in, ybuf, pb, n, sbuf);
    topk_kernel<<<cdiv(B_ * 64, 256), 256, 0, stream>>>(sbuf, n, k, top, loc);
    pool_gather_kernel<<<cdiv(B_ * k * H_, 256), 256, 0, stream>>>(h, top, loc, n, k, xpb, perm);
    if (adjp)
      adj_gather_kernel<<<cdiv(B_ * k * k, 256), 256, 0, stream>>>(adj_in, loc, n, k, adjp);
  };

  // ---- precompute ----
  wcat_kernel<<<cdiv(39 * 512, 256), 256, 0, stream>>>(w_mlp1, 39, 256, wcat1);
  wcat_kernel<<<cdiv(256 * 512, 256), 256, 0, stream>>>(w_mlp2, 256, 256, wcat2);
  wcat_kernel<<<cdiv(256 * 512, 256), 256, 0, stream>>>(w_mlp3, 256, 256, wcat3);
  wcat_kernel<<<cdiv(256 * 78, 256), 256, 0, stream>>>(w_mlp6, 256, 39, wcat6);
  degree_kernel<<<cdiv(4992, 256), 256, 0, stream>>>(adj, deg);

  // ---- level 1 ----
  edge_conv(x, N_, N_, wcat1, b_mlp1, H_, 0, t1);                       // pre-BN h1 -> t1
  bn_stats_kernel<<<H_, 256, 0, stream>>>(t1, 4992, stats);
  bn_apply_kernel<<<cdiv(4992 * 256, 256), 256, 0, stream>>>(t1, stats, bn1_g, bn1_b, 4992, hbuf);
  sag(hbuf, adj, N_, K1_, p1_w, p1_b, top1, loc1, perm1, xp, adj1);     // xp1
  hipMemsetAsync(xout, 0, (size_t)4992 * 256 * 4, stream);
  scatter_kernel<<<cdiv(4096 * 256, 256), 256, 0, stream>>>(xp, perm1, nullptr, 4096, xout);
  // degree head (once, from x_out1)
  gemm(xout, lin4_w, lin4_b, t1, 4992, 256, 256, 1);
  gemm(t1, lin5_w, lin5_b, t2, 4992, 128, 256, 1);
  rowdot_kernel<<<cdiv(4992 * 64, 256), 256, 0, stream>>>(t2, lin6_w, 4992, 128, lin6_b, 1, xdeg);
  gtpred_kernel<<<cdiv(4096, 256), 256, 0, stream>>>(deg, xdeg, perm1, 4096, out_gt1, out_pred1);
  readout_kernel<<<cdiv(128 * 256, 256), 256, 0, stream>>>(xp, K1_, 0, z);
  decoder(xout, out_dec1);

  // ---- level 2 ----
  edge_conv(xp, K1_, H_, wcat2, b_mlp2, H_, 0, t1);                     // pre-BN h2 (M=4096)
  bn_stats_kernel<<<H_, 256, 0, stream>>>(t1, 4096, stats);
  bn_apply_kernel<<<cdiv(4096 * 256, 256), 256, 0, stream>>>(t1, stats, bn2_g, bn2_b, 4096, hbuf);
  sag(hbuf, adj1, K1_, K2_, p2_w, p2_b, top2, loc2, perm2, xp, adj2);   // xp2 (overwrites xp)
  hipMemsetAsync(xout, 0, (size_t)4992 * 256 * 4, stream);
  scatter_kernel<<<cdiv(3328 * 256, 256), 256, 0, stream>>>(xp, perm1, perm2, 3328, xout);
  gtpred_kernel<<<cdiv(3328, 256), 256, 0, stream>>>(deg, xdeg, perm2, 3328, out_gt2, out_pred2);
  readout_kernel<<<cdiv(128 * 256, 256), 256, 0, stream>>>(xp, K2_, 1, z);
  decoder(xout, out_dec2);

  // ---- level 3 ----
  edge_conv(xp, K2_, H_, wcat3, b_mlp3, H_, 0, t1);                     // pre-BN h3 (M=3328)
  bn_stats_kernel<<<H_, 256, 0, stream>>>(t1, 3328, stats);
  bn_apply_kernel<<<cdiv(3328 * 256, 256), 256, 0, stream>>>(t1, stats, bn3_g, bn3_b, 3328, hbuf);
  sag(hbuf, adj2, K2_, K3_, p3_w, p3_b, top3, loc3, perm3, xp, nullptr); // xp3; adj3 unused
  hipMemsetAsync(xout, 0, (size_t)4992 * 256 * 4, stream);
  scatter_kernel<<<cdiv(2688 * 256, 256), 256, 0, stream>>>(xp, perm2, perm3, 2688, xout);
  gtpred_kernel<<<cdiv(2688, 256), 256, 0, stream>>>(deg, xdeg, perm3, 2688, out_gt3, out_pred3);
  readout_kernel<<<cdiv(128 * 256, 256), 256, 0, stream>>>(xp, K3_, 1, z);
  decoder(xout, out_dec3);

  // ---- classifier head (thin: M=128) ----
  rowgemm_kernel<<<128, 256, 0, stream>>>(z, lin1_w, lin1_b, z1, 256, 512, 1);
  rowgemm_kernel<<<128, 256, 0, stream>>>(z1, lin2_w, lin2_b, z2, 128, 256, 1);
  wavedot_gemm_kernel<<<cdiv(128 * 2 * 64, 256), 256, 0, stream>>>(z2, lin3_w, lin3_b, logits, 128, 2, 128, 0);
  softmax2_kernel<<<1, 128, 0, stream>>>(logits, out_probs);
}

// Round 5
// 1353.258 us; speedup vs baseline: 1.6834x; 1.2823x over previous
//
#include <hip/hip_runtime.h>
#include <cmath>

#define B_   128
#define N_   39
#define KNN_ 10
#define H_   256
#define K1_  32
#define K2_  26
#define K3_  21

static inline int cdiv(int a, int b) { return (a + b - 1) / b; }

typedef __attribute__((ext_vector_type(8))) short short8;
typedef __attribute__((ext_vector_type(4))) float floatx4;

__device__ inline short f2b(float f) {   // fp32 -> bf16 RNE
  unsigned u = __float_as_uint(f);
  u += 0x7fff + ((u >> 16) & 1);
  return (short)(u >> 16);
}
__device__ inline float b2f(short h) {
  return __uint_as_float(((unsigned)(unsigned short)h) << 16);
}
__device__ inline void f2b2(float v, short& hi, short& lo) {  // split: v ~= hi + lo
  hi = f2b(v);
  lo = f2b(v - b2f(hi));
}

// ---------- wave-wide argmax/argmin (64 lanes), ties -> lowest index ----------
__device__ inline void wave_argmax64(float& v, int& j) {
#pragma unroll
  for (int off = 32; off; off >>= 1) {
    float ov = __shfl_down(v, off, 64);
    int   oj = __shfl_down(j, off, 64);
    if (ov > v || (ov == v && oj < j)) { v = ov; j = oj; }
  }
  v = __shfl(v, 0, 64);
  j = __shfl(j, 0, 64);
}
__device__ inline void wave_argmin64(float& v, int& j) {
#pragma unroll
  for (int off = 32; off; off >>= 1) {
    float ov = __shfl_down(v, off, 64);
    int   oj = __shfl_down(j, off, 64);
    if (ov < v || (ov == v && oj < j)) { v = ov; j = oj; }
  }
  v = __shfl(v, 0, 64);
  j = __shfl(j, 0, 64);
}

// wc[k][c] = c<H ? w_top[k][c]-w_bot[k][c] : w_bot[k][c-H]   (w is (2F,H) row-major)
__global__ void wcat_kernel(const float* __restrict__ w, int F, int Hc, float* __restrict__ wc) {
  int t = blockIdx.x * blockDim.x + threadIdx.x;
  int total = F * 2 * Hc;
  if (t >= total) return;
  int k = t / (2 * Hc);
  int c = t - k * 2 * Hc;
  if (c < Hc) wc[t] = w[k * Hc + c] - w[(F + k) * Hc + c];
  else        wc[t] = w[(F + k) * Hc + (c - Hc)];
}

// split-bf16 transposed cast: w (K x N fp32) -> wt_h/wt_l (N x K bf16 pair)
__global__ void castT_split_kernel(const float* __restrict__ w, int K, int N,
                                   short* __restrict__ wth, short* __restrict__ wtl) {
  int t = blockIdx.x * blockDim.x + threadIdx.x;
  if (t >= K * N) return;
  int k = t / N, n = t - k * N;
  short hi, lo;
  f2b2(w[t], hi, lo);
  wth[(size_t)n * K + k] = hi;
  wtl[(size_t)n * K + k] = lo;
}

__global__ void degree_kernel(const float* __restrict__ adj, float* __restrict__ deg) {
  int t = blockIdx.x * blockDim.x + threadIdx.x;
  if (t >= B_ * N_) return;
  const float* row = adj + (size_t)t * N_;
  float s = 0.f;
  for (int j = 0; j < N_; ++j) s += row[j];
  deg[t] = s;
}

// Block-per-graph Gram: G[b,i,j] = dot(x[b,i], x[b,j]).
// LDS stride F+4; rt-fast lane mapping: B-rows broadcast across lanes, A-rows 2-way max.
__global__ __launch_bounds__(256) void gram_kernel(const float* __restrict__ x, int n, int F,
                                                   float* __restrict__ G) {
  extern __shared__ float xs[];
  int S = F + 4;
  int b = blockIdx.x;
  const float* xb = x + (size_t)b * n * F;
  for (int t = threadIdx.x; t < 40 * S; t += 256) {
    int r = t / S, f = t - r * S;
    xs[t] = (r < n && f < F) ? xb[r * F + f] : 0.f;
  }
  __syncthreads();
  int rtiles = (n + 1) >> 1;   // rows of 2
  int ctiles = (n + 3) >> 2;   // cols of 4
  float* Gb = G + (size_t)b * n * n;
  for (int t = threadIdx.x; t < rtiles * ctiles; t += 256) {
    int rt = t % rtiles, ct = t / rtiles;   // rt fast -> B-side broadcast
    int i0 = rt * 2, j0 = ct * 4;
    float acc[2][4] = {};
    if ((F & 3) == 0) {
      for (int f = 0; f < F; f += 4) {
        float4 a0 = *(const float4*)&xs[i0 * S + f];
        float4 a1 = *(const float4*)&xs[(i0 + 1) * S + f];
#pragma unroll
        for (int j = 0; j < 4; ++j) {
          float4 bv = *(const float4*)&xs[(j0 + j) * S + f];
          acc[0][j] += a0.x * bv.x + a0.y * bv.y + a0.z * bv.z + a0.w * bv.w;
          acc[1][j] += a1.x * bv.x + a1.y * bv.y + a1.z * bv.z + a1.w * bv.w;
        }
      }
    } else {
      for (int f = 0; f < F; ++f) {
        float a0 = xs[i0 * S + f], a1 = xs[(i0 + 1) * S + f];
#pragma unroll
        for (int j = 0; j < 4; ++j) {
          float bv = xs[(j0 + j) * S + f];
          acc[0][j] += a0 * bv;
          acc[1][j] += a1 * bv;
        }
      }
    }
#pragma unroll
    for (int i = 0; i < 2; ++i) {
      if (i0 + i >= n) continue;
#pragma unroll
      for (int j = 0; j < 4; ++j) {
        if (j0 + j >= n) continue;
        Gb[(i0 + i) * n + (j0 + j)] = acc[i][j];
      }
    }
  }
}

// one wave per row i: K nearest (smallest d), ties -> lowest index (stable like lax.top_k)
__global__ void knn_kernel(const float* __restrict__ G, int n, int M, int* __restrict__ idx) {
  int w = (blockIdx.x * blockDim.x + threadIdx.x) >> 6;
  int lane = threadIdx.x & 63;
  if (w >= M) return;
  int b = w / n;
  int i = w - b * n;
  const float* Gb = G + (size_t)b * n * n;
  float d = INFINITY;
  if (lane < n)
    d = Gb[i * n + i] + Gb[lane * n + lane] - 2.f * Gb[i * n + lane];
  int* out = idx + (size_t)w * KNN_;
  float cur = d;
  for (int kk = 0; kk < KNN_; ++kk) {
    float rv = cur;
    int rj = (lane < n) ? lane : (1 << 20);
    wave_argmin64(rv, rj);
    if (lane == 0) out[kk] = rj;
    if (lane == rj) cur = INFINITY;
  }
}

// ---------------- fp32 tiled GEMM (trunk: feeds top-k, stays fp32) ----------------
#define BM 128
#define BN 64
#define BK 16
#define TM 8
#define TN 4
__global__ __launch_bounds__(256) void gemm_kernel(
    const float* __restrict__ A, const float* __restrict__ W, const float* __restrict__ bias,
    float* __restrict__ C, int M, int N, int K, int act) {
  __shared__ float As[BK][BM + 4];
  __shared__ float Bs[BK][BN + 4];
  int tid = threadIdx.x;
  int tx = tid & 15, ty = tid >> 4;
  int row0 = blockIdx.y * BM, col0 = blockIdx.x * BN;
  float c[TM][TN] = {};
  for (int k0 = 0; k0 < K; k0 += BK) {
    for (int e = tid; e < BM * BK; e += 256) {
      int m = e >> 4, kk = e & 15;
      int row = row0 + m, k = k0 + kk;
      As[kk][m] = (row < M && k < K) ? A[(size_t)row * K + k] : 0.f;
    }
    for (int e = tid; e < BK * BN; e += 256) {
      int kk = e >> 6, nn = e & 63;
      int k = k0 + kk, col = col0 + nn;
      Bs[kk][nn] = (k < K && col < N) ? W[(size_t)k * N + col] : 0.f;
    }
    __syncthreads();
#pragma unroll
    for (int kk = 0; kk < BK; ++kk) {
      float4 a0 = *(const float4*)&As[kk][ty * TM];
      float4 a1 = *(const float4*)&As[kk][ty * TM + 4];
      float4 bv = *(const float4*)&Bs[kk][tx * TN];
      float a[TM] = {a0.x, a0.y, a0.z, a0.w, a1.x, a1.y, a1.z, a1.w};
      float b[TN] = {bv.x, bv.y, bv.z, bv.w};
#pragma unroll
      for (int i = 0; i < TM; ++i)
#pragma unroll
        for (int j = 0; j < TN; ++j) c[i][j] += a[i] * b[j];
    }
    __syncthreads();
  }
  for (int i = 0; i < TM; ++i) {
    int row = row0 + ty * TM + i;
    if (row >= M) continue;
    for (int j = 0; j < TN; ++j) {
      int col = col0 + tx * TN + j;
      if (col >= N) continue;
      float v = c[i][j] + (bias ? bias[col] : 0.f);
      if (act == 1) v = fmaxf(v, 0.f);
      C[(size_t)row * N + col] = v;
    }
  }
}

// ------------- split-bf16 3-pass MFMA GEMM (near-fp32 accuracy, ~2^-16 rel) -------------
// A = Ah+Al (M x K bf16 pairs, row-major). W = Wh+Wl, pre-transposed (N x K bf16 pairs).
// acc += Ah*Wh + Ah*Wl + Al*Wh.  C fp32 [+bias][relu]; optional split-bf16 copy Ch/Cl.
// 128x128 tile, 2x2 waves, each wave 64x64 via 4x4 mfma_f32_16x16x32_bf16.
// LDS row stride 40 shorts (80 B): b128-aligned, max 2-way bank aliasing (free).
__global__ __launch_bounds__(256) void mfma_gemm_split_kernel(
    const short* __restrict__ Ah, const short* __restrict__ Al,
    const short* __restrict__ Wth, const short* __restrict__ Wtl,
    const float* __restrict__ bias,
    float* __restrict__ C, short* __restrict__ Ch, short* __restrict__ Cl,
    int M, int N, int K, int act) {
  __shared__ short Ash[128 * 40];
  __shared__ short Asl[128 * 40];
  __shared__ short Bsh[128 * 40];
  __shared__ short Bsl[128 * 40];
  int tid = threadIdx.x;
  int wave = tid >> 6, lane = tid & 63;
  int wm = wave & 1, wn = wave >> 1;
  int row0 = blockIdx.y * 128, col0 = blockIdx.x * 128;
  floatx4 acc[4][4] = {};
  int lm = lane & 15, lk = (lane >> 4) * 8;
  for (int k0 = 0; k0 < K; k0 += 32) {
    for (int c = tid; c < 512; c += 256) {
      int r = c >> 2, kc = (c & 3) * 8;
      int grow = row0 + r;
      short8 vh = {}, vl = {};
      if (grow < M) {
        vh = *(const short8*)&Ah[(size_t)grow * K + k0 + kc];
        vl = *(const short8*)&Al[(size_t)grow * K + k0 + kc];
      }
      *(short8*)&Ash[r * 40 + kc] = vh;
      *(short8*)&Asl[r * 40 + kc] = vl;
    }
    for (int c = tid; c < 512; c += 256) {
      int r = c >> 2, kc = (c & 3) * 8;
      int gn = col0 + r;
      short8 vh = {}, vl = {};
      if (gn < N) {
        vh = *(const short8*)&Wth[(size_t)gn * K + k0 + kc];
        vl = *(const short8*)&Wtl[(size_t)gn * K + k0 + kc];
      }
      *(short8*)&Bsh[r * 40 + kc] = vh;
      *(short8*)&Bsl[r * 40 + kc] = vl;
    }
    __syncthreads();
    short8 afh[4], afl[4], bfh[4], bfl[4];
#pragma unroll
    for (int mi = 0; mi < 4; ++mi) {
      int ro = (wm * 64 + mi * 16 + lm) * 40 + lk;
      afh[mi] = *(const short8*)&Ash[ro];
      afl[mi] = *(const short8*)&Asl[ro];
    }
#pragma unroll
    for (int ni = 0; ni < 4; ++ni) {
      int ro = (wn * 64 + ni * 16 + lm) * 40 + lk;
      bfh[ni] = *(const short8*)&Bsh[ro];
      bfl[ni] = *(const short8*)&Bsl[ro];
    }
#pragma unroll
    for (int mi = 0; mi < 4; ++mi)
#pragma unroll
      for (int ni = 0; ni < 4; ++ni) {
        acc[mi][ni] = __builtin_amdgcn_mfma_f32_16x16x32_bf16(afh[mi], bfh[ni], acc[mi][ni], 0, 0, 0);
        acc[mi][ni] = __builtin_amdgcn_mfma_f32_16x16x32_bf16(afh[mi], bfl[ni], acc[mi][ni], 0, 0, 0);
        acc[mi][ni] = __builtin_amdgcn_mfma_f32_16x16x32_bf16(afl[mi], bfh[ni], acc[mi][ni], 0, 0, 0);
      }
    __syncthreads();
  }
  int lr = (lane >> 4) * 4;
#pragma unroll
  for (int mi = 0; mi < 4; ++mi)
#pragma unroll
    for (int ni = 0; ni < 4; ++ni) {
      int colg = col0 + wn * 64 + ni * 16 + lm;
      if (colg >= N) continue;
      float bv = bias ? bias[colg] : 0.f;
#pragma unroll
      for (int r = 0; r < 4; ++r) {
        int rowg = row0 + wm * 64 + mi * 16 + lr + r;
        if (rowg >= M) continue;
        float v = acc[mi][ni][r] + bv;
        if (act == 1) v = fmaxf(v, 0.f);
        C[(size_t)rowg * N + colg] = v;
        if (Ch) {
          short hi, lo;
          f2b2(v, hi, lo);
          Ch[(size_t)rowg * N + colg] = hi;
          Cl[(size_t)rowg * N + colg] = lo;
        }
      }
    }
}

// Thin GEMM (small M): one block per row.
__global__ __launch_bounds__(256) void rowgemm_kernel(
    const float* __restrict__ A, const float* __restrict__ W, const float* __restrict__ bias,
    float* __restrict__ C, int N, int K, int act) {
  __shared__ float a[512];
  int row = blockIdx.x;
  for (int k = threadIdx.x; k < K; k += 256) a[k] = A[(size_t)row * K + k];
  __syncthreads();
  for (int c = threadIdx.x; c < N; c += 256) {
    float s = 0.f;
    for (int k = 0; k < K; k += 4) {
      float4 av = *(const float4*)&a[k];
      s += av.x * W[(size_t)k * N + c];
      s += av.y * W[(size_t)(k + 1) * N + c];
      s += av.z * W[(size_t)(k + 2) * N + c];
      s += av.w * W[(size_t)(k + 3) * N + c];
    }
    float v = s + (bias ? bias[c] : 0.f);
    if (act == 1) v = fmaxf(v, 0.f);
    C[(size_t)row * N + c] = v;
  }
}

// one wave per output element (for very small M*N)
__global__ void wavedot_gemm_kernel(const float* __restrict__ A, const float* __restrict__ W,
                                    const float* __restrict__ bias, float* __restrict__ C,
                                    int M, int N, int K, int act) {
  int wid = (blockIdx.x * blockDim.x + threadIdx.x) >> 6;
  int lane = threadIdx.x & 63;
  if (wid >= M * N) return;
  int row = wid / N, col = wid - row * N;
  const float* ar = A + (size_t)row * K;
  float s = 0.f;
  for (int k = lane; k < K; k += 64) s += ar[k] * W[(size_t)k * N + col];
  for (int off = 32; off; off >>= 1) s += __shfl_down(s, off, 64);
  if (lane == 0) {
    float v = s + (bias ? bias[col] : 0.f);
    if (act == 1) v = fmaxf(v, 0.f);
    C[(size_t)row * N + col] = v;
  }
}

// AB row r: [0..Hc) = xi@(Wt-Wb), [Hc..2Hc) = xi@Wb.  out = max_k relu(Ai + b + Bm[nbr]) [tanh]
// optional split-bf16 dual write
__global__ void edge_agg_kernel(const float* __restrict__ AB, const float* __restrict__ bias,
                                const int* __restrict__ idx, int n, int Hc, int act,
                                float* __restrict__ out,
                                short* __restrict__ outh, short* __restrict__ outl) {
  int t = blockIdx.x * blockDim.x + threadIdx.x;
  if (t >= B_ * n * Hc) return;
  int r = t / Hc, h = t - r * Hc;
  int b = r / n;
  int s2 = 2 * Hc;
  float av = AB[(size_t)r * s2 + h] + bias[h];
  const int* ir = idx + (size_t)r * KNN_;
  int base = b * n;
  float m = -INFINITY;
  for (int k = 0; k < KNN_; ++k) {
    float v = av + AB[(size_t)(base + ir[k]) * s2 + Hc + h];
    v = fmaxf(v, 0.f);
    m = fmaxf(m, v);
  }
  if (act == 2) m = tanhf(m);
  out[t] = m;
  if (outh) {
    short hi, lo;
    f2b2(m, hi, lo);
    outh[t] = hi;
    outl[t] = lo;
  }
}

__global__ void bn_stats_kernel(const float* __restrict__ x, int M, float* __restrict__ mv) {
  int c = blockIdx.x;
  double s = 0.0, s2 = 0.0;
  for (int r = threadIdx.x; r < M; r += 256) {
    double v = (double)x[(size_t)r * H_ + c];
    s += v; s2 += v * v;
  }
  __shared__ double sh[256], sh2[256];
  sh[threadIdx.x] = s; sh2[threadIdx.x] = s2;
  __syncthreads();
  for (int o = 128; o; o >>= 1) {
    if (threadIdx.x < o) { sh[threadIdx.x] += sh[threadIdx.x + o]; sh2[threadIdx.x] += sh2[threadIdx.x + o]; }
    __syncthreads();
  }
  if (threadIdx.x == 0) {
    double mean = sh[0] / M;
    double var = sh2[0] / M - mean * mean;
    mv[c] = (float)mean;
    mv[H_ + c] = (float)var;
  }
}

__global__ void bn_apply_kernel(const float* __restrict__ x, const float* __restrict__ mv,
                                const float* __restrict__ g, const float* __restrict__ bb,
                                int M, float* __restrict__ out) {
  int t = blockIdx.x * blockDim.x + threadIdx.x;
  if (t >= M * H_) return;
  int h = t & (H_ - 1);
  float mean = mv[h], var = mv[H_ + h];
  float v = (x[t] - mean) * (1.f / sqrtf(var + 1e-5f)) * g[h] + bb[h];
  out[t] = fmaxf(v, 0.f);
}

// one wave per row: y[r] = dot(x[r,:K], w) [+bias] [relu]
__global__ void rowdot_kernel(const float* __restrict__ x, const float* __restrict__ w,
                              int M, int K, const float* __restrict__ bias, int act,
                              float* __restrict__ y) {
  int wid = (blockIdx.x * blockDim.x + threadIdx.x) >> 6;
  int lane = threadIdx.x & 63;
  if (wid >= M) return;
  const float* xr = x + (size_t)wid * K;
  float s = 0.f;
  for (int k = lane; k < K; k += 64) s += xr[k] * w[k];
  for (int off = 32; off; off >>= 1) s += __shfl_down(s, off, 64);
  if (lane == 0) {
    float v = s + (bias ? bias[0] : 0.f);
    if (act == 1) v = fmaxf(v, 0.f);
    y[wid] = v;
  }
}

// s[b,i] = dinv_i * sum_j (adj+I)_ij * dinv_j * y_j + pb ; dinv = rsqrt(rowsum(adj+I))
__global__ void gcn_score_kernel(const float* __restrict__ adj, const float* __restrict__ y,
                                 const float* __restrict__ pb, int n, float* __restrict__ s) {
  int b = blockIdx.x;
  __shared__ float dinv[64], ys[64];
  int i = threadIdx.x;
  if (i < n) {
    const float* ar = adj + ((size_t)b * n + i) * n;
    float sum = 1.f;
    for (int j = 0; j < n; ++j) sum += ar[j];
    dinv[i] = 1.f / sqrtf(sum);
    ys[i] = y[b * n + i];
  }
  __syncthreads();
  if (i < n) {
    const float* ar = adj + ((size_t)b * n + i) * n;
    float acc = 0.f;
    for (int j = 0; j < n; ++j) {
      float a = ar[j] + (i == j ? 1.f : 0.f);
      acc += a * dinv[j] * ys[j];
    }
    s[b * n + i] = dinv[i] * acc + pb[0];
  }
}

// one wave per graph: descending top-k, stable ties (lowest index first)
__global__ void topk_kernel(const float* __restrict__ s, int n, int k,
                            float* __restrict__ top, int* __restrict__ loc) {
  int w = (blockIdx.x * blockDim.x + threadIdx.x) >> 6;
  int lane = threadIdx.x & 63;
  if (w >= B_) return;
  float cur = (lane < n) ? s[w * n + lane] : -INFINITY;
  for (int t = 0; t < k; ++t) {
    float rv = cur;
    int rj = (lane < n) ? lane : (1 << 20);
    wave_argmax64(rv, rj);
    if (lane == 0) { top[w * k + t] = rv; loc[w * k + t] = rj; }
    if (lane == rj) cur = -INFINITY;
  }
}

__global__ void pool_gather_kernel(const float* __restrict__ h, const float* __restrict__ top,
                                   const int* __restrict__ loc, int n, int k,
                                   float* __restrict__ xp, int* __restrict__ perm) {
  int t = blockIdx.x * blockDim.x + threadIdx.x;
  if (t >= B_ * k * H_) return;
  int r = t / H_, hh = t - r * H_;
  int b = r / k;
  int l = loc[r];
  xp[t] = h[((size_t)(b * n + l)) * H_ + hh] * tanhf(top[r]);
  if (hh == 0) perm[r] = b * n + l;
}

__global__ void adj_gather_kernel(const float* __restrict__ adj, const int* __restrict__ loc,
                                  int n, int k, float* __restrict__ adjp) {
  int t = blockIdx.x * blockDim.x + threadIdx.x;
  if (t >= B_ * k * k) return;
  int b = t / (k * k);
  int r = t - b * k * k;
  int t1 = r / k, t2 = r - t1 * k;
  adjp[t] = adj[((size_t)b * n + loc[b * k + t1]) * n + loc[b * k + t2]];
}

// dst[i1[i2[r]] or i1[r]] = src[r]; fp32 + split-bf16 (all pre-zeroed)
__global__ void scatter_kernel(const float* __restrict__ src, const int* __restrict__ i1,
                               const int* __restrict__ i2, int rows,
                               float* __restrict__ dst,
                               short* __restrict__ dsth, short* __restrict__ dstl) {
  int t = blockIdx.x * blockDim.x + threadIdx.x;
  if (t >= rows * H_) return;
  int r = t / H_, h = t - r * H_;
  int tgt = i2 ? i1[i2[r]] : i1[r];
  float v = src[t];
  dst[(size_t)tgt * H_ + h] = v;
  short hi, lo;
  f2b2(v, hi, lo);
  dsth[(size_t)tgt * H_ + h] = hi;
  dstl[(size_t)tgt * H_ + h] = lo;
}

__global__ void gtpred_kernel(const float* __restrict__ deg, const float* __restrict__ xdeg,
                              const int* __restrict__ perm, int M,
                              float* __restrict__ gt, float* __restrict__ pred) {
  int t = blockIdx.x * blockDim.x + threadIdx.x;
  if (t >= M) return;
  int p = perm[t];
  gt[t] = deg[p];
  pred[t] = xdeg[p];
}

__global__ void readout_kernel(const float* __restrict__ xp, int k, int acc, float* __restrict__ z) {
  int t = blockIdx.x * blockDim.x + threadIdx.x;
  if (t >= B_ * H_) return;
  int b = t / H_, h = t - b * H_;
  float mx = -INFINITY, sm = 0.f;
  for (int tt = 0; tt < k; ++tt) {
    float v = xp[((size_t)b * k + tt) * H_ + h];
    mx = fmaxf(mx, v);
    sm += v;
  }
  float* zb = z + (size_t)b * 2 * H_;
  float mean = sm / (float)k;
  if (acc) { zb[h] += mx; zb[H_ + h] += mean; }
  else     { zb[h] = mx;  zb[H_ + h] = mean; }
}

__global__ void softmax2_kernel(const float* __restrict__ logits, float* __restrict__ probs) {
  int b = blockIdx.x * blockDim.x + threadIdx.x;
  if (b >= B_) return;
  float a = logits[2 * b], c = logits[2 * b + 1];
  float m = fmaxf(a, c);
  float ea = expf(a - m), ec = expf(c - m);
  float inv = 1.f / (ea + ec);
  probs[2 * b] = ea * inv;
  probs[2 * b + 1] = ec * inv;
}

extern "C" void kernel_launch(void* const* d_in, const int* in_sizes, int n_in,
                              void* d_out, int out_size, void* d_ws, size_t ws_size,
                              hipStream_t stream) {
  auto in = [&](int i) { return (const float*)d_in[i]; };
  const float* x      = in(0);
  const float* adj    = in(1);
  const float* w_mlp1 = in(2);  const float* b_mlp1 = in(3);
  const float* w_mlp2 = in(4);  const float* b_mlp2 = in(5);
  const float* w_mlp3 = in(6);  const float* b_mlp3 = in(7);
  const float* w_mlp6 = in(8);  const float* b_mlp6 = in(9);
  const float* bn1_g = in(10);  const float* bn1_b = in(11);
  const float* bn2_g = in(12);  const float* bn2_b = in(13);
  const float* bn3_g = in(14);  const float* bn3_b = in(15);
  const float* p1_w = in(16);   const float* p1_b = in(17);
  const float* p2_w = in(18);   const float* p2_b = in(19);
  const float* p3_w = in(20);   const float* p3_b = in(21);
  const float* lin1_w = in(22); const float* lin1_b = in(23);
  const float* lin2_w = in(24); const float* lin2_b = in(25);
  const float* lin3_w = in(26); const float* lin3_b = in(27);
  const float* lin4_w = in(28); const float* lin4_b = in(29);
  const float* lin5_w = in(30); const float* lin5_b = in(31);
  const float* lin6_w = in(32); const float* lin6_b = in(33);

  float* out = (float*)d_out;
  float* out_probs = out;                      // 128*2
  float* out_dec1  = out_probs + 256;          // 4992*39
  float* out_dec2  = out_dec1 + 4992 * 39;
  float* out_dec3  = out_dec2 + 4992 * 39;
  float* out_gt1   = out_dec3 + 4992 * 39;     // 4096
  float* out_pred1 = out_gt1 + 4096;           // 4096
  float* out_gt2   = out_pred1 + 4096;         // 3328
  float* out_pred2 = out_gt2 + 3328;
  float* out_gt3   = out_pred2 + 3328;         // 2688
  float* out_pred3 = out_gt3 + 2688;

  char* base = (char*)d_ws;
  size_t off = 0;
  auto allocf = [&](size_t n) -> float* {
    float* p = (float*)(base + off);
    off += ((n * sizeof(float) + 255) & ~(size_t)255);
    return p;
  };
  auto alloci = [&](size_t n) -> int* {
    int* p = (int*)(base + off);
    off += ((n * sizeof(int) + 255) & ~(size_t)255);
    return p;
  };
  auto allocs = [&](size_t n) -> short* {
    short* p = (short*)(base + off);
    off += ((n * sizeof(short) + 255) & ~(size_t)255);
    return p;
  };

  float* wcat1 = allocf(39 * 512);
  float* wcat2 = allocf(256 * 512);
  float* wcat3 = allocf(256 * 512);
  float* wcat6 = allocf(256 * 78);
  short* wcat2t_h = allocs(512 * 256); short* wcat2t_l = allocs(512 * 256);
  short* wcat3t_h = allocs(512 * 256); short* wcat3t_l = allocs(512 * 256);
  short* wcat6t_h = allocs(78 * 256);  short* wcat6t_l = allocs(78 * 256);
  short* lin4t_h  = allocs(256 * 256); short* lin4t_l  = allocs(256 * 256);
  short* lin5t_h  = allocs(128 * 256); short* lin5t_l  = allocs(128 * 256);
  float* deg   = allocf(4992);
  float* xdeg  = allocf(4992);
  float* ybuf  = allocf(4992);
  float* sbuf  = allocf(4992);
  float* stats = allocf(512);
  float* G     = allocf(128 * 39 * 39);
  int*   idxb  = alloci(4992 * KNN_);
  float* AB    = allocf((size_t)4992 * 512);
  float* t1    = allocf((size_t)4992 * 256);
  float* t2    = allocf((size_t)4992 * 256);
  float* hbuf  = allocf((size_t)4992 * 256);
  float* xp    = allocf((size_t)4096 * 256);
  float* xout  = allocf((size_t)4992 * 256);
  short* xout_h = allocs((size_t)4992 * 256); short* xout_l = allocs((size_t)4992 * 256);
  short* t1_h   = allocs((size_t)4992 * 256); short* t1_l   = allocs((size_t)4992 * 256);
  short* t2_h   = allocs((size_t)4992 * 256); short* t2_l   = allocs((size_t)4992 * 256);
  float* adj1  = allocf(128 * 32 * 32);
  float* adj2  = allocf(128 * 26 * 26);
  float* top1  = allocf(4096);
  float* top2  = allocf(3328);
  float* top3  = allocf(2688);
  int* loc1 = alloci(4096); int* loc2 = alloci(3328); int* loc3 = alloci(2688);
  int* perm1 = alloci(4096); int* perm2 = alloci(3328); int* perm3 = alloci(2688);
  float* z  = allocf(128 * 512);
  float* z1 = allocf(128 * 256);
  float* z2 = allocf(128 * 128);
  float* logits = allocf(256);
  if (off > ws_size) return;  // workspace too small — fail loudly via poisoned output

  // fp32 trunk edge conv (feeds top-k; exact)
  auto edge_conv = [&](const float* xin, int n, int F, const float* wcat, const float* bias,
                       int Hout, float* outbuf) {
    int M = B_ * n;
    gram_kernel<<<B_, 256, 40 * (F + 4) * sizeof(float), stream>>>(xin, n, F, G);
    knn_kernel<<<cdiv(M * 64, 256), 256, 0, stream>>>(G, n, M, idxb);
    dim3 gg(cdiv(2 * Hout, BN), cdiv(M, BM));
    gemm_kernel<<<gg, 256, 0, stream>>>(xin, wcat, nullptr, AB, M, 2 * Hout, F, 0);
    edge_agg_kernel<<<cdiv(M * Hout, 256), 256, 0, stream>>>(AB, bias, idxb, n, Hout, 0, outbuf, nullptr, nullptr);
  };
  // split-bf16 decoder edge conv: fp32 gram/knn on xin; 3-pass MFMA on split input
  auto edge_conv_bf = [&](const float* xin, const short* xh, const short* xl,
                          const short* wth, const short* wtl,
                          const float* bias, int Hout, int act,
                          float* outbuf, short* outh, short* outl) {
    int M = 4992, F = 256;
    gram_kernel<<<B_, 256, 40 * (F + 4) * sizeof(float), stream>>>(xin, N_, F, G);
    knn_kernel<<<cdiv(M * 64, 256), 256, 0, stream>>>(G, N_, M, idxb);
    dim3 gg(cdiv(2 * Hout, 128), cdiv(M, 128));
    mfma_gemm_split_kernel<<<gg, 256, 0, stream>>>(xh, xl, wth, wtl, nullptr, AB, nullptr, nullptr,
                                                   M, 2 * Hout, F, 0);
    edge_agg_kernel<<<cdiv(M * Hout, 256), 256, 0, stream>>>(AB, bias, idxb, N_, Hout, act, outbuf, outh, outl);
  };
  auto decoder = [&](const float* xin, const short* xh, const short* xl, float* decout) {
    edge_conv_bf(xin, xh, xl, wcat3t_h, wcat3t_l, b_mlp3, H_, 2, t1, t1_h, t1_l);
    edge_conv_bf(t1, t1_h, t1_l, wcat2t_h, wcat2t_l, b_mlp2, H_, 2, t2, t2_h, t2_l);
    edge_conv_bf(t2, t2_h, t2_l, wcat6t_h, wcat6t_l, b_mlp6, N_, 0, decout, nullptr, nullptr);
  };
  auto gemm = [&](const float* A, const float* W, const float* bias, float* C,
                  int M, int N, int K, int act) {
    dim3 gg(cdiv(N, BN), cdiv(M, BM));
    gemm_kernel<<<gg, 256, 0, stream>>>(A, W, bias, C, M, N, K, act);
  };
  auto sag = [&](const float* h, const float* adj_in, int n, int k,
                 const float* pw, const float* pb,
                 float* top, int* loc, int* perm, float* xpb, float* adjp) {
    int M = B_ * n;
    rowdot_kernel<<<cdiv(M * 64, 256), 256, 0, stream>>>(h, pw, M, H_, nullptr, 0, ybuf);
    gcn_score_kernel<<<B_, 64, 0, stream>>>(adj_in, ybuf, pb, n, sbuf);
    topk_kernel<<<cdiv(B_ * 64, 256), 256, 0, stream>>>(sbuf, n, k, top, loc);
    pool_gather_kernel<<<cdiv(B_ * k * H_, 256), 256, 0, stream>>>(h, top, loc, n, k, xpb, perm);
    if (adjp)
      adj_gather_kernel<<<cdiv(B_ * k * k, 256), 256, 0, stream>>>(adj_in, loc, n, k, adjp);
  };

  // ---- precompute ----
  wcat_kernel<<<cdiv(39 * 512, 256), 256, 0, stream>>>(w_mlp1, 39, 256, wcat1);
  wcat_kernel<<<cdiv(256 * 512, 256), 256, 0, stream>>>(w_mlp2, 256, 256, wcat2);
  wcat_kernel<<<cdiv(256 * 512, 256), 256, 0, stream>>>(w_mlp3, 256, 256, wcat3);
  wcat_kernel<<<cdiv(256 * 78, 256), 256, 0, stream>>>(w_mlp6, 256, 39, wcat6);
  castT_split_kernel<<<cdiv(256 * 512, 256), 256, 0, stream>>>(wcat2, 256, 512, wcat2t_h, wcat2t_l);
  castT_split_kernel<<<cdiv(256 * 512, 256), 256, 0, stream>>>(wcat3, 256, 512, wcat3t_h, wcat3t_l);
  castT_split_kernel<<<cdiv(256 * 78, 256), 256, 0, stream>>>(wcat6, 256, 78, wcat6t_h, wcat6t_l);
  castT_split_kernel<<<cdiv(256 * 256, 256), 256, 0, stream>>>(lin4_w, 256, 256, lin4t_h, lin4t_l);
  castT_split_kernel<<<cdiv(256 * 128, 256), 256, 0, stream>>>(lin5_w, 256, 128, lin5t_h, lin5t_l);
  degree_kernel<<<cdiv(4992, 256), 256, 0, stream>>>(adj, deg);

  // ---- level 1 ----
  edge_conv(x, N_, N_, wcat1, b_mlp1, H_, t1);                          // pre-BN h1 -> t1
  bn_stats_kernel<<<H_, 256, 0, stream>>>(t1, 4992, stats);
  bn_apply_kernel<<<cdiv(4992 * 256, 256), 256, 0, stream>>>(t1, stats, bn1_g, bn1_b, 4992, hbuf);
  sag(hbuf, adj, N_, K1_, p1_w, p1_b, top1, loc1, perm1, xp, adj1);     // xp1
  hipMemsetAsync(xout, 0, (size_t)4992 * 256 * 4, stream);
  hipMemsetAsync(xout_h, 0, (size_t)4992 * 256 * 2, stream);
  hipMemsetAsync(xout_l, 0, (size_t)4992 * 256 * 2, stream);
  scatter_kernel<<<cdiv(4096 * 256, 256), 256, 0, stream>>>(xp, perm1, nullptr, 4096, xout, xout_h, xout_l);
  // degree head (once, from x_out1) — split-bf16 MFMA
  {
    dim3 g4(2, 39);
    mfma_gemm_split_kernel<<<g4, 256, 0, stream>>>(xout_h, xout_l, lin4t_h, lin4t_l, lin4_b,
                                                   t1, t1_h, t1_l, 4992, 256, 256, 1);
    dim3 g5(1, 39);
    mfma_gemm_split_kernel<<<g5, 256, 0, stream>>>(t1_h, t1_l, lin5t_h, lin5t_l, lin5_b,
                                                   t2, nullptr, nullptr, 4992, 128, 256, 1);
  }
  rowdot_kernel<<<cdiv(4992 * 64, 256), 256, 0, stream>>>(t2, lin6_w, 4992, 128, lin6_b, 1, xdeg);
  gtpred_kernel<<<cdiv(4096, 256), 256, 0, stream>>>(deg, xdeg, perm1, 4096, out_gt1, out_pred1);
  readout_kernel<<<cdiv(128 * 256, 256), 256, 0, stream>>>(xp, K1_, 0, z);
  decoder(xout, xout_h, xout_l, out_dec1);

  // ---- level 2 ----
  edge_conv(xp, K1_, H_, wcat2, b_mlp2, H_, t1);                        // pre-BN h2 (M=4096)
  bn_stats_kernel<<<H_, 256, 0, stream>>>(t1, 4096, stats);
  bn_apply_kernel<<<cdiv(4096 * 256, 256), 256, 0, stream>>>(t1, stats, bn2_g, bn2_b, 4096, hbuf);
  sag(hbuf, adj1, K1_, K2_, p2_w, p2_b, top2, loc2, perm2, xp, adj2);   // xp2 (overwrites xp)
  hipMemsetAsync(xout, 0, (size_t)4992 * 256 * 4, stream);
  hipMemsetAsync(xout_h, 0, (size_t)4992 * 256 * 2, stream);
  hipMemsetAsync(xout_l, 0, (size_t)4992 * 256 * 2, stream);
  scatter_kernel<<<cdiv(3328 * 256, 256), 256, 0, stream>>>(xp, perm1, perm2, 3328, xout, xout_h, xout_l);
  gtpred_kernel<<<cdiv(3328, 256), 256, 0, stream>>>(deg, xdeg, perm2, 3328, out_gt2, out_pred2);
  readout_kernel<<<cdiv(128 * 256, 256), 256, 0, stream>>>(xp, K2_, 1, z);
  decoder(xout, xout_h, xout_l, out_dec2);

  // ---- level 3 ----
  edge_conv(xp, K2_, H_, wcat3, b_mlp3, H_, t1);                        // pre-BN h3 (M=3328)
  bn_stats_kernel<<<H_, 256, 0, stream>>>(t1, 3328, stats);
  bn_apply_kernel<<<cdiv(3328 * 256, 256), 256, 0, stream>>>(t1, stats, bn3_g, bn3_b, 3328, hbuf);
  sag(hbuf, adj2, K2_, K3_, p3_w, p3_b, top3, loc3, perm3, xp, nullptr); // xp3; adj3 unused
  hipMemsetAsync(xout, 0, (size_t)4992 * 256 * 4, stream);
  hipMemsetAsync(xout_h, 0, (size_t)4992 * 256 * 2, stream);
  hipMemsetAsync(xout_l, 0, (size_t)4992 * 256 * 2, stream);
  scatter_kernel<<<cdiv(2688 * 256, 256), 256, 0, stream>>>(xp, perm2, perm3, 2688, xout, xout_h, xout_l);
  gtpred_kernel<<<cdiv(2688, 256), 256, 0, stream>>>(deg, xdeg, perm3, 2688, out_gt3, out_pred3);
  readout_kernel<<<cdiv(128 * 256, 256), 256, 0, stream>>>(xp, K3_, 1, z);
  decoder(xout, xout_h, xout_l, out_dec3);

  // ---- classifier head (thin: M=128) ----
  rowgemm_kernel<<<128, 256, 0, stream>>>(z, lin1_w, lin1_b, z1, 256, 512, 1);
  rowgemm_kernel<<<128, 256, 0, stream>>>(z1, lin2_w, lin2_b, z2, 128, 256, 1);
  wavedot_gemm_kernel<<<cdiv(128 * 2 * 64, 256), 256, 0, stream>>>(z2, lin3_w, lin3_b, logits, 128, 2, 128, 0);
  softmax2_kernel<<<1, 128, 0, stream>>>(logits, out_probs);
}